// Round 1
// baseline (749.371 us; speedup 1.0000x reference)
//
#include <hip/hip_runtime.h>
#include <hip/hip_bf16.h>

// Problem constants
#define N_ROWS 65536   // 16*4096
#define EDIM   512
#define NCODES 1024

// ws layout (floats): [0]=loss, [1..1025)=counts, [1025..2049)=enorm, [2049..)=znorm
#define WS_LOSS   0
#define WS_COUNTS 1
#define WS_ENORM  1025
#define WS_ZNORM  2049
#define WS_AMBCNT (2049 + 65536)          // int, 67585
#define WS_WINNER (WS_AMBCNT + 1)         // 65536 ints
#define WS_AMBLST (WS_WINNER + 65536)     // CAP ints
#define AMB_CAP   32768
#define WS_E2_OFF (1u << 20)              // e2 (bf16 hi/lo) at ws + 1 MiB, 2 MiB
#define WS_FAST_BYTES (3u * 1024u * 1024u + 4096u)

// δ bound: ref quantization 2×ULP(512)/2 = 6.1e-5, ref-vs-my dot ≈ 6.3e-6 → pair 1.35e-4
#define AMB_EPS 1.6e-4f

typedef short short8 __attribute__((ext_vector_type(8)));
typedef float f32x4  __attribute__((ext_vector_type(4)));

#define AS1C(p) ((const __attribute__((address_space(1))) void*)(p))
#define AS3(p)  ((__attribute__((address_space(3))) void*)(p))

static __device__ __forceinline__ unsigned short f2bf(float f) {
    unsigned u = __float_as_uint(f);
    u += 0x7FFFu + ((u >> 16) & 1u);   // RNE (finite inputs only)
    return (unsigned short)(u >> 16);
}
static __device__ __forceinline__ float bf2f(unsigned short h) {
    return __uint_as_float(((unsigned)h) << 16);
}

// ---------------- kernel: codebook norms + zero accumulators ----------------
__global__ __launch_bounds__(256) void vq_prep(const float* __restrict__ cb,
                                               float* __restrict__ ws) {
    int j = blockIdx.x;
    int tid = threadIdx.x;
    float2 v = *(const float2*)&cb[(size_t)j * EDIM + tid * 2];
    float s = v.x * v.x + v.y * v.y;
    #pragma unroll
    for (int off = 32; off > 0; off >>= 1) s += __shfl_down(s, off);
    __shared__ float ls[4];
    int wave = tid >> 6, lane = tid & 63;
    if (lane == 0) ls[wave] = s;
    __syncthreads();
    if (tid == 0) {
        ws[WS_ENORM + j] = ls[0] + ls[1] + ls[2] + ls[3];
        ws[WS_COUNTS + j] = 0.0f;
        if (j == 0) {
            ws[WS_LOSS] = 0.0f;
            ((int*)ws)[WS_AMBCNT] = 0;
        }
    }
}

// ---------------- kernel: per-row ||z||^2, numpy-pairwise bit-exact ----------------
__global__ __launch_bounds__(256) void vq_znorm(const float* __restrict__ z,
                                                float* __restrict__ ws) {
    int tid  = threadIdx.x;
    int lrow = tid >> 5;
    int c    = tid & 31;
    long row = (long)blockIdx.x * 8 + lrow;
    const float* p = z + row * EDIM + (c >> 3) * 128 + (c & 7);
    float r = p[0] * p[0];
    #pragma unroll
    for (int i = 1; i < 16; ++i) {
        float v = p[i * 8];
        r += v * v;
    }
    r += __shfl_xor(r, 1);
    r += __shfl_xor(r, 2);
    r += __shfl_xor(r, 4);
    r += __shfl_xor(r, 8);
    r += __shfl_xor(r, 16);
    if (c == 0) ws[WS_ZNORM + row] = r;
}

// ---------------- kernel: z -> bf16 hi/lo panels ----------------
// layout: [panel p][kc 0..15][plane hi/lo][row 0..127][k 0..31] ushort
__global__ __launch_bounds__(256) void vq_convz(const float* __restrict__ z,
                                                unsigned short* __restrict__ z2) {
    const int tid = threadIdx.x;
    const int p = blockIdx.x;
    const long row0 = (long)p * 128;
    const int row = tid >> 1, half = tid & 1;
    for (int kc = 0; kc < 16; ++kc) {
        const float* src = z + (row0 + row) * EDIM + kc * 32 + half * 16;
        float f[16];
        #pragma unroll
        for (int q = 0; q < 4; ++q) {
            float4 v = ((const float4*)src)[q];
            f[q*4+0] = v.x; f[q*4+1] = v.y; f[q*4+2] = v.z; f[q*4+3] = v.w;
        }
        unsigned hi[8], lo[8];
        #pragma unroll
        for (int q = 0; q < 8; ++q) {
            unsigned short h0 = f2bf(f[2*q]);
            unsigned short h1 = f2bf(f[2*q+1]);
            unsigned short l0 = f2bf(f[2*q]   - bf2f(h0));
            unsigned short l1 = f2bf(f[2*q+1] - bf2f(h1));
            hi[q] = (unsigned)h0 | ((unsigned)h1 << 16);
            lo[q] = (unsigned)l0 | ((unsigned)l1 << 16);
        }
        size_t base = ((size_t)(p * 16 + kc) * 2) * 4096;
        unsigned* dhi = (unsigned*)(z2 + base        + row * 32 + half * 16);
        unsigned* dlo = (unsigned*)(z2 + base + 4096 + row * 32 + half * 16);
        ((uint4*)dhi)[0] = make_uint4(hi[0], hi[1], hi[2], hi[3]);
        ((uint4*)dhi)[1] = make_uint4(hi[4], hi[5], hi[6], hi[7]);
        ((uint4*)dlo)[0] = make_uint4(lo[0], lo[1], lo[2], lo[3]);
        ((uint4*)dlo)[1] = make_uint4(lo[4], lo[5], lo[6], lo[7]);
    }
}

// ---------------- kernel: cb -> bf16 hi/lo panels ----------------
// layout: [cc 0..7][kc 0..15][plane][code 0..127][k 0..31]
__global__ __launch_bounds__(256) void vq_convcb(const float* __restrict__ cb,
                                                 unsigned short* __restrict__ e2) {
    const int tid = threadIdx.x;
    const int cc = blockIdx.x;
    const int row = tid >> 1, half = tid & 1;
    for (int kc = 0; kc < 16; ++kc) {
        const float* src = cb + (size_t)(cc * 128 + row) * EDIM + kc * 32 + half * 16;
        float f[16];
        #pragma unroll
        for (int q = 0; q < 4; ++q) {
            float4 v = ((const float4*)src)[q];
            f[q*4+0] = v.x; f[q*4+1] = v.y; f[q*4+2] = v.z; f[q*4+3] = v.w;
        }
        unsigned hi[8], lo[8];
        #pragma unroll
        for (int q = 0; q < 8; ++q) {
            unsigned short h0 = f2bf(f[2*q]);
            unsigned short h1 = f2bf(f[2*q+1]);
            unsigned short l0 = f2bf(f[2*q]   - bf2f(h0));
            unsigned short l1 = f2bf(f[2*q+1] - bf2f(h1));
            hi[q] = (unsigned)h0 | ((unsigned)h1 << 16);
            lo[q] = (unsigned)l0 | ((unsigned)l1 << 16);
        }
        size_t base = ((size_t)(cc * 16 + kc) * 2) * 4096;
        unsigned* dhi = (unsigned*)(e2 + base        + row * 32 + half * 16);
        unsigned* dlo = (unsigned*)(e2 + base + 4096 + row * 32 + half * 16);
        ((uint4*)dhi)[0] = make_uint4(hi[0], hi[1], hi[2], hi[3]);
        ((uint4*)dhi)[1] = make_uint4(hi[4], hi[5], hi[6], hi[7]);
        ((uint4*)dlo)[0] = make_uint4(lo[0], lo[1], lo[2], lo[3]);
        ((uint4*)dlo)[1] = make_uint4(lo[4], lo[5], lo[6], lo[7]);
    }
}

// ---------------- main MFMA kernel: d-hat + per-row top2 + ambiguity ----------------
// NEW STRUCTURE (2-phase pipelined):
//   block tile 128 rows x 256 codes per pass (4 passes over 1024 codes),
//   8 waves (2 row-groups x 4 code-groups), wave tile 64x64, mfma 16x16x32 bf16.
//   Per kc-step: issue next-step's 48 KB stage (z 16K + e 32K) via global_load_lds
//   into the OTHER buffer FIRST, then ds_read frags + 48 MFMAs on current buffer,
//   then s_waitcnt vmcnt(0) + raw s_barrier. No compiler vmcnt-drain mid-step;
//   stage latency hides under the MFMA cluster. z2 re-read 4x (was 8x).
//   Accumulation chain per (row,code) is bit-identical to the previous kernel
//   (hihi,hilo,lohi chained over kc 0..15 from zero), so AMB_EPS analysis holds.
__device__ __forceinline__ void stage48(const char* zs, const char* es0, const char* es1,
                                        char* db, int tid, int w) {
    const int t16 = tid << 4;
    const int wb  = w << 10;   // wave-uniform LDS base; HW adds lane*16
    __builtin_amdgcn_global_load_lds(AS1C(zs + t16),         AS3(db + wb),          16, 0, 0);
    __builtin_amdgcn_global_load_lds(AS1C(zs + 8192 + t16),  AS3(db + 8192 + wb),   16, 0, 0);
    __builtin_amdgcn_global_load_lds(AS1C(es0 + t16),        AS3(db + 16384 + wb),  16, 0, 0);
    __builtin_amdgcn_global_load_lds(AS1C(es0 + 8192 + t16), AS3(db + 24576 + wb),  16, 0, 0);
    __builtin_amdgcn_global_load_lds(AS1C(es1 + t16),        AS3(db + 32768 + wb),  16, 0, 0);
    __builtin_amdgcn_global_load_lds(AS1C(es1 + 8192 + t16), AS3(db + 40960 + wb),  16, 0, 0);
}

__global__ __launch_bounds__(512, 2) void vq_mfma(const unsigned short* __restrict__ z2,
                                                  const unsigned short* __restrict__ e2,
                                                  const float* __restrict__ ws,
                                                  int* __restrict__ winner,
                                                  int* __restrict__ amb_count,
                                                  int* __restrict__ amb_list) {
    __shared__ __attribute__((aligned(16))) char sb[2][49152];  // 96 KB double-buffer
    __shared__ float enorm_lds[NCODES];                         // 4 KB
    __shared__ float fv1[4][128];
    __shared__ float fv2[4][128];
    __shared__ int   fc1[4][128];

    const int tid  = threadIdx.x;
    const int lane = tid & 63, w = tid >> 6;
    const int rw   = (w & 1) * 64;     // row offset of wave tile
    const int wcol = w >> 1;           // 0..3 code-group
    const int cw   = wcol * 64;        // code offset within 256-wide pass
    const int ml = lane & 15, kg = lane >> 4;
    const long row0 = (long)blockIdx.x * 128;

    // enorm -> LDS (epilogue reads stay off the vmcnt path)
    enorm_lds[tid]       = ws[WS_ENORM + tid];
    enorm_lds[tid + 512] = ws[WS_ENORM + tid + 512];

    float v1[16], v2[16];
    int   c1[16];
    #pragma unroll
    for (int i = 0; i < 16; ++i) { v1[i] = INFINITY; v2[i] = INFINITY; c1[i] = 0; }

    const size_t zpan = (size_t)blockIdx.x * 16 * 8192;   // ushort offset of this row-panel

    // prologue: stage step 0 (pass 0, kc 0) into buf 0
    stage48((const char*)(z2 + zpan),
            (const char*)e2,
            (const char*)(e2 + (size_t)16 * 8192),
            sb[0], tid, w);
    __syncthreads();   // full drain once; buf0 ready

    int cur = 0;
    for (int p = 0; p < 4; ++p) {
        f32x4 acc[4][4];
        #pragma unroll
        for (int rt = 0; rt < 4; ++rt)
            #pragma unroll
            for (int ct = 0; ct < 4; ++ct)
                acc[rt][ct] = (f32x4){0.f, 0.f, 0.f, 0.f};

        #pragma unroll 2
        for (int kc = 0; kc < 16; ++kc) {
            const int s = p * 16 + kc;
            // 1) issue NEXT step's stage into the other buffer (safe: that buffer's
            //    readers all passed the previous step's barrier)
            if (s + 1 < 64) {
                const int s2 = s + 1, p2 = s2 >> 4, kc2 = s2 & 15;
                const char* zs  = (const char*)(z2 + zpan + (size_t)kc2 * 8192);
                const char* es0 = (const char*)(e2 + ((size_t)(2 * p2)     * 16 + kc2) * 8192);
                const char* es1 = (const char*)(e2 + ((size_t)(2 * p2 + 1) * 16 + kc2) * 8192);
                stage48(zs, es0, es1, sb[cur ^ 1], tid, w);
            }
            // 2) frag reads from current buffer + MFMAs (covers the stage latency)
            const unsigned short* zt = (const unsigned short*)sb[cur];
            const unsigned short* et = (const unsigned short*)(sb[cur] + 16384);
            short8 a[4][2], b[4][2];
            #pragma unroll
            for (int rt = 0; rt < 4; ++rt) {
                a[rt][0] = *(const short8*)&zt[        (rw + rt * 16 + ml) * 32 + kg * 8];
                a[rt][1] = *(const short8*)&zt[4096 + (rw + rt * 16 + ml) * 32 + kg * 8];
            }
            #pragma unroll
            for (int ct = 0; ct < 4; ++ct) {
                const int c2  = cw + ct * 16 + ml;                       // 0..255
                const int off = (c2 >> 7) * 8192 + (c2 & 127) * 32 + kg * 8;
                b[ct][0] = *(const short8*)&et[off];
                b[ct][1] = *(const short8*)&et[off + 4096];
            }
            #pragma unroll
            for (int rt = 0; rt < 4; ++rt)
                #pragma unroll
                for (int ct = 0; ct < 4; ++ct) {
                    acc[rt][ct] = __builtin_amdgcn_mfma_f32_16x16x32_bf16(a[rt][0], b[ct][0], acc[rt][ct], 0, 0, 0);
                    acc[rt][ct] = __builtin_amdgcn_mfma_f32_16x16x32_bf16(a[rt][0], b[ct][1], acc[rt][ct], 0, 0, 0);
                    acc[rt][ct] = __builtin_amdgcn_mfma_f32_16x16x32_bf16(a[rt][1], b[ct][0], acc[rt][ct], 0, 0, 0);
                }
            // 3) ensure next buffer fully staged, then raw barrier (no lgkm/vm drift)
            asm volatile("s_waitcnt vmcnt(0)" ::: "memory");
            __builtin_amdgcn_s_barrier();
            asm volatile("" ::: "memory");
            cur ^= 1;
        }

        // epilogue: d-hat = enorm - 2*dot, per-lane top2 per row (codes ascend per lane)
        #pragma unroll
        for (int ct = 0; ct < 4; ++ct) {
            const int code = p * 256 + cw + ct * 16 + ml;
            const float en = enorm_lds[code];
            #pragma unroll
            for (int rt = 0; rt < 4; ++rt)
                #pragma unroll
                for (int reg = 0; reg < 4; ++reg) {
                    float d = fmaf(-2.0f, acc[rt][ct][reg], en);
                    int i = rt * 4 + reg;
                    bool lt1 = d < v1[i];
                    bool lt2 = d < v2[i];
                    v2[i] = lt1 ? v1[i] : (lt2 ? d : v2[i]);
                    v1[i] = lt1 ? d : v1[i];
                    c1[i] = lt1 ? code : c1[i];
                }
        }
    }

    // cross-lane merge among the 16 lanes (same kg) sharing each row
    #pragma unroll
    for (int i = 0; i < 16; ++i) {
        #pragma unroll
        for (int off = 1; off < 16; off <<= 1) {
            float ov1 = __shfl_xor(v1[i], off);
            int   oc1 = __shfl_xor(c1[i], off);
            float ov2 = __shfl_xor(v2[i], off);
            bool take = (ov1 < v1[i]) || (ov1 == v1[i] && oc1 < c1[i]);
            float nv2 = take ? fminf(v1[i], ov2) : fminf(v2[i], ov1);
            v1[i] = take ? ov1 : v1[i];
            c1[i] = take ? oc1 : c1[i];
            v2[i] = nv2;
        }
    }
    __syncthreads();
    if (ml == 0) {
        #pragma unroll
        for (int i = 0; i < 16; ++i) {
            int row = rw + (i >> 2) * 16 + kg * 4 + (i & 3);
            fv1[wcol][row] = v1[i];
            fv2[wcol][row] = v2[i];
            fc1[wcol][row] = c1[i];
        }
    }
    __syncthreads();
    if (tid < 128) {
        float V1 = fv1[0][tid], V2 = fv2[0][tid];
        int   C1 = fc1[0][tid];
        #pragma unroll
        for (int g = 1; g < 4; ++g) {
            float b1 = fv1[g][tid], b2 = fv2[g][tid];
            int   bc = fc1[g][tid];
            bool take = (b1 < V1) || (b1 == V1 && bc < C1);
            float nv2 = take ? fminf(V1, b2) : fminf(V2, b1);
            V1 = take ? b1 : V1;
            C1 = take ? bc : C1;
            V2 = nv2;
        }
        winner[row0 + tid] = C1;
        if (V2 - V1 < AMB_EPS) {
            int pq = atomicAdd(amb_count, 1);
            if (pq < AMB_CAP) amb_list[pq] = (int)(row0 + tid);
        }
    }
}

// ---------------- recheck v2: batched exact R2-chain argmin ----------------
// 8 rows/batch staged transposed in LDS; each thread keeps codes {tid,tid+256,
// tid+512,tid+768} with the identical sequential 16x32-chunk association.
#define RB 8
#define ZSR 9   // padded row stride in zs (breaks bank conflicts on staging writes)
__global__ __launch_bounds__(256) void vq_recheck(const float* __restrict__ z,
                                                  const float* __restrict__ cb,
                                                  const float* __restrict__ ws,
                                                  int* __restrict__ winner,
                                                  const int* __restrict__ amb_count,
                                                  const int* __restrict__ amb_list) {
    __shared__ float zs[EDIM * ZSR];     // [k][r] transposed, 18KB
    __shared__ float wred_d[4];
    __shared__ int   wred_i[4];
    const int tid = threadIdx.x;
    const int lane = tid & 63, wv = tid >> 6;
    const float* __restrict__ enorm = ws + WS_ENORM;

    int n = *amb_count;
    bool overflow = (n > AMB_CAP);
    if (overflow) n = N_ROWS;            // safety net: recheck every row
    int nIter = (n + RB - 1) / RB;

    const float* ec[4];
    float en4[4];
    #pragma unroll
    for (int c = 0; c < 4; ++c) {
        ec[c]  = cb + (size_t)(tid + 256 * c) * EDIM;
        en4[c] = enorm[tid + 256 * c];
    }

    for (int ii = blockIdx.x; ii < nIter; ii += gridDim.x) {
        int rows[RB];
        #pragma unroll
        for (int j = 0; j < RB; ++j) {
            int idx = ii * RB + j;
            if (idx >= n) idx = n - 1;
            rows[j] = overflow ? idx : amb_list[idx];
        }
        __syncthreads();
        #pragma unroll
        for (int j = 0; j < RB; ++j) {
            float2 v = *(const float2*)&z[(long)rows[j] * EDIM + tid * 2];
            zs[(tid * 2 + 0) * ZSR + j] = v.x;
            zs[(tid * 2 + 1) * ZSR + j] = v.y;
        }
        __syncthreads();

        float acc[RB][4];
        #pragma unroll
        for (int r = 0; r < RB; ++r)
            #pragma unroll
            for (int c = 0; c < 4; ++c) acc[r][c] = 0.0f;

        for (int k0 = 0; k0 < EDIM; k0 += 32) {
            float ain[RB][4];
            #pragma unroll
            for (int r = 0; r < RB; ++r)
                #pragma unroll
                for (int c = 0; c < 4; ++c) ain[r][c] = 0.0f;
            #pragma unroll
            for (int ks = 0; ks < 32; ks += 8) {
                float er[4][8];
                #pragma unroll
                for (int c = 0; c < 4; ++c) {
                    float4 a = *(const float4*)&ec[c][k0 + ks];
                    float4 b = *(const float4*)&ec[c][k0 + ks + 4];
                    er[c][0]=a.x; er[c][1]=a.y; er[c][2]=a.z; er[c][3]=a.w;
                    er[c][4]=b.x; er[c][5]=b.y; er[c][6]=b.z; er[c][7]=b.w;
                }
                #pragma unroll
                for (int kk = 0; kk < 8; ++kk) {
                    const float* zp = &zs[(k0 + ks + kk) * ZSR];
                    float4 z0 = *(const float4*)zp;       // rows 0..3 (broadcast)
                    float4 z1 = *(const float4*)(zp + 4); // rows 4..7
                    float zr[RB] = {z0.x, z0.y, z0.z, z0.w, z1.x, z1.y, z1.z, z1.w};
                    #pragma unroll
                    for (int r = 0; r < RB; ++r)
                        #pragma unroll
                        for (int c = 0; c < 4; ++c)
                            ain[r][c] = fmaf(zr[r], er[c][kk], ain[r][c]);
                }
            }
            #pragma unroll
            for (int r = 0; r < RB; ++r)
                #pragma unroll
                for (int c = 0; c < 4; ++c) acc[r][c] += ain[r][c];
        }

        // per-row: d = fl(fl(zn+en) - 2*acc), first-index argmin
        #pragma unroll
        for (int r = 0; r < RB; ++r) {
            float zn = ws[WS_ZNORM + rows[r]];
            float bd = INFINITY;
            int   bc = 0;
            #pragma unroll
            for (int c = 0; c < 4; ++c) {        // codes ascending per thread
                float t = zn + en4[c];
                float d = t - 2.0f * acc[r][c];
                if (d < bd) { bd = d; bc = tid + 256 * c; }
            }
            // wave reduce with index tiebreak
            #pragma unroll
            for (int off = 1; off < 64; off <<= 1) {
                float od = __shfl_xor(bd, off);
                int   oi = __shfl_xor(bc, off);
                if (od < bd || (od == bd && oi < bc)) { bd = od; bc = oi; }
            }
            if (lane == 0) { wred_d[wv] = bd; wred_i[wv] = bc; }
            __syncthreads();
            if (tid == 0) {
                float fd = wred_d[0]; int fi = wred_i[0];
                #pragma unroll
                for (int t2 = 1; t2 < 4; ++t2) {
                    if (wred_d[t2] < fd || (wred_d[t2] == fd && wred_i[t2] < fi)) {
                        fd = wred_d[t2]; fi = wred_i[t2];
                    }
                }
                winner[rows[r]] = fi;
            }
            __syncthreads();
        }
    }
}

// ---------------- emit: idx, counts, z_q_st, loss ----------------
__global__ __launch_bounds__(256) void vq_emit(const float* __restrict__ z,
                                               const float* __restrict__ cb,
                                               const int* __restrict__ winner,
                                               float* __restrict__ ws,
                                               float* __restrict__ out_zq,
                                               float* __restrict__ out_idx) {
    __shared__ float lred[4];
    const int tid = threadIdx.x;
    const long row0 = (long)blockIdx.x * 128;
    if (tid < 128) {
        int wi = winner[row0 + tid];
        out_idx[row0 + tid] = (float)wi;
        atomicAdd(&ws[WS_COUNTS + wi], 1.0f);
    }
    float lsum = 0.0f;
    for (int r = 0; r < 128; ++r) {
        int wv = winner[row0 + r];
        float2 e  = *(const float2*)&cb[(size_t)wv * EDIM + tid * 2];
        float2 zz = *(const float2*)&z[(row0 + r) * EDIM + tid * 2];
        float d0 = e.x - zz.x, d1 = e.y - zz.y;
        float2 o; o.x = zz.x + d0; o.y = zz.y + d1;
        *(float2*)&out_zq[(row0 + r) * EDIM + tid * 2] = o;
        lsum = fmaf(d0, d0, fmaf(d1, d1, lsum));
    }
    #pragma unroll
    for (int off = 32; off > 0; off >>= 1) lsum += __shfl_down(lsum, off);
    int wave = tid >> 6, lane = tid & 63;
    if (lane == 0) lred[wave] = lsum;
    __syncthreads();
    if (tid == 0) atomicAdd(&ws[WS_LOSS], lred[0] + lred[1] + lred[2] + lred[3]);
}

// ---------------- finalize loss + perplexity ----------------
__global__ __launch_bounds__(1024) void vq_final(const float* __restrict__ ws,
                                                 float* __restrict__ out,
                                                 long off_perp) {
    int tid = threadIdx.x;
    float c = ws[WS_COUNTS + tid] * (1.0f / (float)N_ROWS);
    float t = c * logf(c + 1e-10f);
    #pragma unroll
    for (int off = 32; off > 0; off >>= 1) t += __shfl_down(t, off);
    __shared__ float ls[16];
    int wave = tid >> 6, lane = tid & 63;
    if (lane == 0) ls[wave] = t;
    __syncthreads();
    if (tid == 0) {
        float h = 0.0f;
        #pragma unroll
        for (int i = 0; i < 16; ++i) h += ls[i];
        out[off_perp] = expf(-h);
        out[0] = ws[WS_LOSS] * 1.25f / (float)((long)N_ROWS * EDIM);
    }
}

// ================= fallback: round-2 verified fp32 main kernel =================
#define ROWS_PER_BLOCK 128
#define CODE_CHUNK     64
#define KCHUNK         32
#define ZSTRIDE        132
#define ESTRIDE        68

__global__ __launch_bounds__(256) void vq_main_fb(const float* __restrict__ z,
                                                  const float* __restrict__ cb,
                                                  float* __restrict__ ws,
                                                  float* __restrict__ out_zq,
                                                  float* __restrict__ out_idx) {
    __shared__ float zt[KCHUNK * ZSTRIDE];
    __shared__ float et[KCHUNK * ESTRIDE];
    __shared__ float red_d[ROWS_PER_BLOCK * 8];
    __shared__ int   red_i[ROWS_PER_BLOCK * 8];
    __shared__ int   winner[ROWS_PER_BLOCK];
    __shared__ float lred[4];

    const int tid = threadIdx.x;
    const int tx = tid & 7;
    const int ty = tid >> 3;
    const long row0 = (long)blockIdx.x * ROWS_PER_BLOCK;
    const float* __restrict__ enorm = ws + WS_ENORM;
    const float* __restrict__ znorm = ws + WS_ZNORM;

    float zn[4];
    #pragma unroll
    for (int i = 0; i < 4; ++i) zn[i] = znorm[row0 + ty * 4 + i];

    float best[4];
    int   bidx[4];
    #pragma unroll
    for (int i = 0; i < 4; ++i) { best[i] = INFINITY; bidx[i] = 0; }

    const int kq    = (tid & 7) * 4;
    const int rbase = tid >> 3;

    for (int c = 0; c < NCODES; c += CODE_CHUNK) {
        float acc[4][8];
        #pragma unroll
        for (int i = 0; i < 4; ++i)
            #pragma unroll
            for (int j = 0; j < 8; ++j) acc[i][j] = 0.0f;

        for (int k0 = 0; k0 < EDIM; k0 += KCHUNK) {
            __syncthreads();
            #pragma unroll
            for (int it = 0; it < 4; ++it) {
                int r = rbase + it * 32;
                float4 v = *(const float4*)&z[(row0 + r) * EDIM + k0 + kq];
                zt[(kq + 0) * ZSTRIDE + r] = v.x;
                zt[(kq + 1) * ZSTRIDE + r] = v.y;
                zt[(kq + 2) * ZSTRIDE + r] = v.z;
                zt[(kq + 3) * ZSTRIDE + r] = v.w;
            }
            #pragma unroll
            for (int it = 0; it < 2; ++it) {
                int e = rbase + it * 32;
                float4 v = *(const float4*)&cb[(size_t)(c + e) * EDIM + k0 + kq];
                et[(kq + 0) * ESTRIDE + e] = v.x;
                et[(kq + 1) * ESTRIDE + e] = v.y;
                et[(kq + 2) * ESTRIDE + e] = v.z;
                et[(kq + 3) * ESTRIDE + e] = v.w;
            }
            __syncthreads();
            float ain[4][8];
            #pragma unroll
            for (int i = 0; i < 4; ++i)
                #pragma unroll
                for (int j = 0; j < 8; ++j) ain[i][j] = 0.0f;
            #pragma unroll
            for (int kk = 0; kk < KCHUNK; ++kk) {
                float4 zv = *(const float4*)&zt[kk * ZSTRIDE + ty * 4];
                float4 e0 = *(const float4*)&et[kk * ESTRIDE + tx * 8];
                float4 e1 = *(const float4*)&et[kk * ESTRIDE + tx * 8 + 4];
                float za[4] = {zv.x, zv.y, zv.z, zv.w};
                float ea[8] = {e0.x, e0.y, e0.z, e0.w, e1.x, e1.y, e1.z, e1.w};
                #pragma unroll
                for (int i = 0; i < 4; ++i)
                    #pragma unroll
                    for (int j = 0; j < 8; ++j)
                        ain[i][j] = fmaf(za[i], ea[j], ain[i][j]);
            }
            #pragma unroll
            for (int i = 0; i < 4; ++i)
                #pragma unroll
                for (int j = 0; j < 8; ++j) acc[i][j] += ain[i][j];
        }
        #pragma unroll
        for (int j = 0; j < 8; ++j) {
            int code = c + tx * 8 + j;
            float en = enorm[code];
            #pragma unroll
            for (int i = 0; i < 4; ++i) {
                float t = zn[i] + en;
                float d = t - 2.0f * acc[i][j];
                if (d < best[i]) { best[i] = d; bidx[i] = code; }
            }
        }
    }

    __syncthreads();
    #pragma unroll
    for (int i = 0; i < 4; ++i) {
        red_d[(ty * 4 + i) * 8 + tx] = best[i];
        red_i[(ty * 4 + i) * 8 + tx] = bidx[i];
    }
    __syncthreads();
    if (tid < ROWS_PER_BLOCK) {
        float bd = red_d[tid * 8];
        int   bi = red_i[tid * 8];
        #pragma unroll
        for (int t = 1; t < 8; ++t) {
            float dv = red_d[tid * 8 + t];
            int   iv = red_i[tid * 8 + t];
            if (dv < bd || (dv == bd && iv < bi)) { bd = dv; bi = iv; }
        }
        winner[tid] = bi;
        out_idx[row0 + tid] = (float)bi;
        atomicAdd(&ws[WS_COUNTS + bi], 1.0f);
    }
    __syncthreads();

    float lsum = 0.0f;
    for (int r = 0; r < ROWS_PER_BLOCK; ++r) {
        int w = winner[r];
        float2 e  = *(const float2*)&cb[(size_t)w * EDIM + tid * 2];
        float2 zz = *(const float2*)&z[(row0 + r) * EDIM + tid * 2];
        float d0 = e.x - zz.x, d1 = e.y - zz.y;
        float2 o; o.x = zz.x + d0; o.y = zz.y + d1;
        *(float2*)&out_zq[(row0 + r) * EDIM + tid * 2] = o;
        lsum = fmaf(d0, d0, fmaf(d1, d1, lsum));
    }
    #pragma unroll
    for (int off = 32; off > 0; off >>= 1) lsum += __shfl_down(lsum, off);
    int wave = tid >> 6, lane = tid & 63;
    if (lane == 0) lred[wave] = lsum;
    __syncthreads();
    if (tid == 0) atomicAdd(&ws[WS_LOSS], lred[0] + lred[1] + lred[2] + lred[3]);
}

extern "C" void kernel_launch(void* const* d_in, const int* in_sizes, int n_in,
                              void* d_out, int out_size, void* d_ws, size_t ws_size,
                              hipStream_t stream) {
    const float* z  = (const float*)d_in[0];
    const float* cb = (const float*)d_in[1];
    float* out = (float*)d_out;
    float* ws  = (float*)d_ws;

    float* out_zq  = out + 1;
    float* out_idx = out + 1 + (long)N_ROWS * EDIM;
    long   off_perp = 1 + (long)N_ROWS * EDIM + N_ROWS;

    hipLaunchKernelGGL(vq_prep, dim3(NCODES), dim3(256), 0, stream, cb, ws);
    hipLaunchKernelGGL(vq_znorm, dim3(N_ROWS / 8), dim3(256), 0, stream, z, ws);

    if (ws_size >= (size_t)WS_FAST_BYTES) {
        // z2 scratch lives in the z_q output region (16B-aligned at out+4;
        // spills 12 B into the idx region, which emit rewrites afterwards)
        unsigned short* z2 = (unsigned short*)(out + 4);
        unsigned short* e2 = (unsigned short*)((char*)d_ws + WS_E2_OFF);
        int* winner    = ((int*)ws) + WS_WINNER;
        int* amb_count = ((int*)ws) + WS_AMBCNT;
        int* amb_list  = ((int*)ws) + WS_AMBLST;

        hipLaunchKernelGGL(vq_convz, dim3(N_ROWS / 128), dim3(256), 0, stream, z, z2);
        hipLaunchKernelGGL(vq_convcb, dim3(8), dim3(256), 0, stream, cb, e2);
        hipLaunchKernelGGL(vq_mfma, dim3(N_ROWS / 128), dim3(512), 0, stream,
                           z2, e2, ws, winner, amb_count, amb_list);
        hipLaunchKernelGGL(vq_recheck, dim3(512), dim3(256), 0, stream,
                           z, cb, ws, winner, amb_count, amb_list);
        hipLaunchKernelGGL(vq_emit, dim3(N_ROWS / 128), dim3(256), 0, stream,
                           z, cb, winner, ws, out_zq, out_idx);
    } else {
        hipLaunchKernelGGL(vq_main_fb, dim3(N_ROWS / 128), dim3(256), 0, stream,
                           z, cb, ws, out_zq, out_idx);
    }
    hipLaunchKernelGGL(vq_final, dim3(1), dim3(1024), 0, stream, ws, out, off_perp);
}

// Round 2
// 713.742 us; speedup vs baseline: 1.0499x; 1.0499x over previous
//
#include <hip/hip_runtime.h>
#include <hip/hip_bf16.h>

// Problem constants
#define N_ROWS 65536   // 16*4096
#define EDIM   512
#define NCODES 1024

// ws layout (floats): [0]=loss, [1..1025)=counts, [1025..2049)=enorm, [2049..)=znorm
#define WS_LOSS   0
#define WS_COUNTS 1
#define WS_ENORM  1025
#define WS_ZNORM  2049
#define WS_AMBCNT (2049 + 65536)          // int, 67585
#define WS_WINNER (WS_AMBCNT + 1)         // 65536 ints
#define WS_AMBLST (WS_WINNER + 65536)     // CAP ints
#define AMB_CAP   32768
#define WS_E2_OFF (1u << 20)              // e2 (bf16 hi/lo) at ws + 1 MiB, 2 MiB
#define WS_FAST_BYTES (3u * 1024u * 1024u + 4096u)

// δ bound: ref quantization 2×ULP(512)/2 = 6.1e-5, ref-vs-my dot ≈ 6.3e-6 → pair 1.35e-4
#define AMB_EPS 1.6e-4f

typedef short short8 __attribute__((ext_vector_type(8)));
typedef float f32x4  __attribute__((ext_vector_type(4)));

#define AS1C(p) ((const __attribute__((address_space(1))) void*)(p))
#define AS3(p)  ((__attribute__((address_space(3))) void*)(p))

static __device__ __forceinline__ unsigned short f2bf(float f) {
    unsigned u = __float_as_uint(f);
    u += 0x7FFFu + ((u >> 16) & 1u);   // RNE (finite inputs only)
    return (unsigned short)(u >> 16);
}
static __device__ __forceinline__ float bf2f(unsigned short h) {
    return __uint_as_float(((unsigned)h) << 16);
}

// ---------------- kernel: codebook norms + zero accumulators ----------------
__global__ __launch_bounds__(256) void vq_prep(const float* __restrict__ cb,
                                               float* __restrict__ ws) {
    int j = blockIdx.x;
    int tid = threadIdx.x;
    float2 v = *(const float2*)&cb[(size_t)j * EDIM + tid * 2];
    float s = v.x * v.x + v.y * v.y;
    #pragma unroll
    for (int off = 32; off > 0; off >>= 1) s += __shfl_down(s, off);
    __shared__ float ls[4];
    int wave = tid >> 6, lane = tid & 63;
    if (lane == 0) ls[wave] = s;
    __syncthreads();
    if (tid == 0) {
        ws[WS_ENORM + j] = ls[0] + ls[1] + ls[2] + ls[3];
        ws[WS_COUNTS + j] = 0.0f;
        if (j == 0) {
            ws[WS_LOSS] = 0.0f;
            ((int*)ws)[WS_AMBCNT] = 0;
        }
    }
}

// ---------------- kernel: per-row ||z||^2, numpy-pairwise bit-exact ----------------
__global__ __launch_bounds__(256) void vq_znorm(const float* __restrict__ z,
                                                float* __restrict__ ws) {
    int tid  = threadIdx.x;
    int lrow = tid >> 5;
    int c    = tid & 31;
    long row = (long)blockIdx.x * 8 + lrow;
    const float* p = z + row * EDIM + (c >> 3) * 128 + (c & 7);
    float r = p[0] * p[0];
    #pragma unroll
    for (int i = 1; i < 16; ++i) {
        float v = p[i * 8];
        r += v * v;
    }
    r += __shfl_xor(r, 1);
    r += __shfl_xor(r, 2);
    r += __shfl_xor(r, 4);
    r += __shfl_xor(r, 8);
    r += __shfl_xor(r, 16);
    if (c == 0) ws[WS_ZNORM + row] = r;
}

// ---------------- kernel: z -> bf16 hi/lo panels ----------------
// layout: [panel p][kc 0..15][plane hi/lo][row 0..127][k 0..31] ushort
__global__ __launch_bounds__(256) void vq_convz(const float* __restrict__ z,
                                                unsigned short* __restrict__ z2) {
    const int tid = threadIdx.x;
    const int p = blockIdx.x;
    const long row0 = (long)p * 128;
    const int row = tid >> 1, half = tid & 1;
    for (int kc = 0; kc < 16; ++kc) {
        const float* src = z + (row0 + row) * EDIM + kc * 32 + half * 16;
        float f[16];
        #pragma unroll
        for (int q = 0; q < 4; ++q) {
            float4 v = ((const float4*)src)[q];
            f[q*4+0] = v.x; f[q*4+1] = v.y; f[q*4+2] = v.z; f[q*4+3] = v.w;
        }
        unsigned hi[8], lo[8];
        #pragma unroll
        for (int q = 0; q < 8; ++q) {
            unsigned short h0 = f2bf(f[2*q]);
            unsigned short h1 = f2bf(f[2*q+1]);
            unsigned short l0 = f2bf(f[2*q]   - bf2f(h0));
            unsigned short l1 = f2bf(f[2*q+1] - bf2f(h1));
            hi[q] = (unsigned)h0 | ((unsigned)h1 << 16);
            lo[q] = (unsigned)l0 | ((unsigned)l1 << 16);
        }
        size_t base = ((size_t)(p * 16 + kc) * 2) * 4096;
        unsigned* dhi = (unsigned*)(z2 + base        + row * 32 + half * 16);
        unsigned* dlo = (unsigned*)(z2 + base + 4096 + row * 32 + half * 16);
        ((uint4*)dhi)[0] = make_uint4(hi[0], hi[1], hi[2], hi[3]);
        ((uint4*)dhi)[1] = make_uint4(hi[4], hi[5], hi[6], hi[7]);
        ((uint4*)dlo)[0] = make_uint4(lo[0], lo[1], lo[2], lo[3]);
        ((uint4*)dlo)[1] = make_uint4(lo[4], lo[5], lo[6], lo[7]);
    }
}

// ---------------- kernel: cb -> bf16 hi/lo panels ----------------
// layout: [cc 0..7][kc 0..15][plane][code 0..127][k 0..31]
__global__ __launch_bounds__(256) void vq_convcb(const float* __restrict__ cb,
                                                 unsigned short* __restrict__ e2) {
    const int tid = threadIdx.x;
    const int cc = blockIdx.x;
    const int row = tid >> 1, half = tid & 1;
    for (int kc = 0; kc < 16; ++kc) {
        const float* src = cb + (size_t)(cc * 128 + row) * EDIM + kc * 32 + half * 16;
        float f[16];
        #pragma unroll
        for (int q = 0; q < 4; ++q) {
            float4 v = ((const float4*)src)[q];
            f[q*4+0] = v.x; f[q*4+1] = v.y; f[q*4+2] = v.z; f[q*4+3] = v.w;
        }
        unsigned hi[8], lo[8];
        #pragma unroll
        for (int q = 0; q < 8; ++q) {
            unsigned short h0 = f2bf(f[2*q]);
            unsigned short h1 = f2bf(f[2*q+1]);
            unsigned short l0 = f2bf(f[2*q]   - bf2f(h0));
            unsigned short l1 = f2bf(f[2*q+1] - bf2f(h1));
            hi[q] = (unsigned)h0 | ((unsigned)h1 << 16);
            lo[q] = (unsigned)l0 | ((unsigned)l1 << 16);
        }
        size_t base = ((size_t)(cc * 16 + kc) * 2) * 4096;
        unsigned* dhi = (unsigned*)(e2 + base        + row * 32 + half * 16);
        unsigned* dlo = (unsigned*)(e2 + base + 4096 + row * 32 + half * 16);
        ((uint4*)dhi)[0] = make_uint4(hi[0], hi[1], hi[2], hi[3]);
        ((uint4*)dhi)[1] = make_uint4(hi[4], hi[5], hi[6], hi[7]);
        ((uint4*)dlo)[0] = make_uint4(lo[0], lo[1], lo[2], lo[3]);
        ((uint4*)dlo)[1] = make_uint4(lo[4], lo[5], lo[6], lo[7]);
    }
}

// ---------------- main MFMA kernel: d-hat + per-row top2 + ambiguity ----------------
// Round-2 structure: 128x128 tile, 4 waves (2 row-groups x 2 code-groups, 64x64
// wave tiles), 2-phase double-buffered 32KB stages with raw-barrier + vmcnt(0),
// 2 blocks/CU (71KB LDS) -> inter-block + intra-block overlap.
// LDS tile layout: interleaved rows [row][hi 64B | lo 64B] (128B rows) with
// XOR swizzle slot ^= (row&7) (bits 4-6; involution since row bits >= 7).
// Staging keeps the linear global_load_lds dest and pre-permutes the GLOBAL
// source per lane; frag reads apply the same XOR -> 2-way (free) bank access.
// Accumulation chain per (row,code) is bit-identical to the verified kernel
// (hihi,hilo,lohi chained over kc 0..15 from zero), so AMB_EPS analysis holds.
__device__ __forceinline__ void stage32(const char* zs, const char* es,
                                        char* db, int goff, int w) {
    const int wb = w << 10;    // wave-uniform LDS base; HW adds lane*16
    #pragma unroll
    for (int i = 0; i < 4; ++i) {
        __builtin_amdgcn_global_load_lds(AS1C(zs + goff + i * 2048),
                                         AS3(db + i * 4096 + wb), 16, 0, 0);
        __builtin_amdgcn_global_load_lds(AS1C(es + goff + i * 2048),
                                         AS3(db + 16384 + i * 4096 + wb), 16, 0, 0);
    }
}

__global__ __launch_bounds__(256, 2) void vq_mfma(const unsigned short* __restrict__ z2,
                                                  const unsigned short* __restrict__ e2,
                                                  const float* __restrict__ ws,
                                                  int* __restrict__ winner,
                                                  int* __restrict__ amb_count,
                                                  int* __restrict__ amb_list) {
    __shared__ __attribute__((aligned(16))) char sb[2][32768];  // 64 KB double-buffer
    __shared__ float enorm_lds[NCODES];                         // 4 KB
    __shared__ float fv1[2][128];
    __shared__ float fv2[2][128];
    __shared__ int   fc1[2][128];

    const int tid  = threadIdx.x;
    const int lane = tid & 63, w = tid >> 6;
    const int rw   = (w & 1) * 64;     // row offset of wave tile
    const int wcol = w >> 1;           // 0..1 code-group
    const int cw   = wcol * 64;        // code offset within 128-wide cc panel
    const int ml = lane & 15, kg = lane >> 4;
    const long row0 = (long)blockIdx.x * 128;

    // staging: per-lane swizzled GLOBAL source offset within a 16KB [hi|lo] panel.
    // LDS physical (linear) byte P = i*4096 + tid*16 -> row = i*32 + (tid>>3),
    // physical slot s' = tid&7 holds logical slot sl = s' ^ (row&7).
    const int t3 = tid >> 3;
    const int sl = (tid & 7) ^ (t3 & 7);
    const int goff = t3 * 64 + (sl & 3) * 16 + (sl >> 2) * 8192;

    // frag reads: logical (row, slot=p*4+kg) lives at row*128 + (slot^(row&7))*16
    const int xr = ml & 7;             // row&7 == ml&7 for all rt/rw (multiples of 8)
    const int o0 = (kg ^ xr) * 16;           // hi plane slot
    const int o1 = ((4 + kg) ^ xr) * 16;     // lo plane slot
    const int za = (rw + ml) * 128;
    const int ea = 16384 + (cw + ml) * 128;

    // enorm -> LDS (keeps epilogue off the vmcnt path)
    #pragma unroll
    for (int i = 0; i < 4; ++i) enorm_lds[tid + i * 256] = ws[WS_ENORM + tid + i * 256];

    float v1[16], v2[16];
    int   c1[16];
    #pragma unroll
    for (int i = 0; i < 16; ++i) { v1[i] = INFINITY; v2[i] = INFINITY; c1[i] = 0; }

    const char* z2b = (const char*)z2 + (size_t)blockIdx.x * 16 * 16384;
    const char* e2b = (const char*)e2;

    f32x4 acc[4][4];
    #pragma unroll
    for (int rt = 0; rt < 4; ++rt)
        #pragma unroll
        for (int ct = 0; ct < 4; ++ct)
            acc[rt][ct] = (f32x4){0.f, 0.f, 0.f, 0.f};

    // prologue: stage step 0 (cc=0, kc=0) into buffer 0
    stage32(z2b, e2b, sb[0], goff, w);
    __syncthreads();   // full drain once; buf0 ready

    int cur = 0;
    #pragma unroll 2
    for (int s = 0; s < 128; ++s) {
        // 1) issue NEXT step's stage into the other buffer (its readers all
        //    passed the previous step's barrier)
        if (s + 1 < 128) {
            const int s2 = s + 1;
            stage32(z2b + (size_t)(s2 & 15) * 16384,
                    e2b + (size_t)s2 * 16384,       // (cc*16+kc)*16KB == s2*16KB
                    sb[cur ^ 1], goff, w);
        }
        // 2) frag reads + 48 MFMAs on current buffer (covers stage latency)
        const char* bz = sb[cur];
        short8 a[4][2], b[4][2];
        #pragma unroll
        for (int rt = 0; rt < 4; ++rt) {
            a[rt][0] = *(const short8*)(bz + za + rt * 2048 + o0);
            a[rt][1] = *(const short8*)(bz + za + rt * 2048 + o1);
        }
        #pragma unroll
        for (int ct = 0; ct < 4; ++ct) {
            b[ct][0] = *(const short8*)(bz + ea + ct * 2048 + o0);
            b[ct][1] = *(const short8*)(bz + ea + ct * 2048 + o1);
        }
        #pragma unroll
        for (int rt = 0; rt < 4; ++rt)
            #pragma unroll
            for (int ct = 0; ct < 4; ++ct) {
                acc[rt][ct] = __builtin_amdgcn_mfma_f32_16x16x32_bf16(a[rt][0], b[ct][0], acc[rt][ct], 0, 0, 0);
                acc[rt][ct] = __builtin_amdgcn_mfma_f32_16x16x32_bf16(a[rt][0], b[ct][1], acc[rt][ct], 0, 0, 0);
                acc[rt][ct] = __builtin_amdgcn_mfma_f32_16x16x32_bf16(a[rt][1], b[ct][0], acc[rt][ct], 0, 0, 0);
            }
        // 3) my stage loads landed; raw barrier (no compiler lgkm/vm drain)
        asm volatile("s_waitcnt vmcnt(0)" ::: "memory");
        __builtin_amdgcn_s_barrier();
        asm volatile("" ::: "memory");
        cur ^= 1;

        // 4) per-cc epilogue (registers + static LDS only; overlaps next stage)
        if ((s & 15) == 15) {
            const int cc = s >> 4;
            #pragma unroll
            for (int ct = 0; ct < 4; ++ct) {
                const int code = cc * 128 + cw + ct * 16 + ml;
                const float en = enorm_lds[code];
                #pragma unroll
                for (int rt = 0; rt < 4; ++rt)
                    #pragma unroll
                    for (int reg = 0; reg < 4; ++reg) {
                        float d = fmaf(-2.0f, acc[rt][ct][reg], en);
                        int i = rt * 4 + reg;
                        bool lt1 = d < v1[i];
                        bool lt2 = d < v2[i];
                        v2[i] = lt1 ? v1[i] : (lt2 ? d : v2[i]);
                        v1[i] = lt1 ? d : v1[i];
                        c1[i] = lt1 ? code : c1[i];
                    }
            }
            #pragma unroll
            for (int rt = 0; rt < 4; ++rt)
                #pragma unroll
                for (int ct = 0; ct < 4; ++ct)
                    acc[rt][ct] = (f32x4){0.f, 0.f, 0.f, 0.f};
        }
    }

    // cross-lane merge among the 16 lanes (same kg) sharing each row
    #pragma unroll
    for (int i = 0; i < 16; ++i) {
        #pragma unroll
        for (int off = 1; off < 16; off <<= 1) {
            float ov1 = __shfl_xor(v1[i], off);
            int   oc1 = __shfl_xor(c1[i], off);
            float ov2 = __shfl_xor(v2[i], off);
            bool take = (ov1 < v1[i]) || (ov1 == v1[i] && oc1 < c1[i]);
            float nv2 = take ? fminf(v1[i], ov2) : fminf(v2[i], ov1);
            v1[i] = take ? ov1 : v1[i];
            c1[i] = take ? oc1 : c1[i];
            v2[i] = nv2;
        }
    }
    __syncthreads();
    if (ml == 0) {
        #pragma unroll
        for (int i = 0; i < 16; ++i) {
            int row = rw + (i >> 2) * 16 + kg * 4 + (i & 3);
            fv1[wcol][row] = v1[i];
            fv2[wcol][row] = v2[i];
            fc1[wcol][row] = c1[i];
        }
    }
    __syncthreads();
    if (tid < 128) {
        float a1 = fv1[0][tid], a2 = fv2[0][tid];
        int   ac = fc1[0][tid];
        float b1 = fv1[1][tid], b2 = fv2[1][tid];
        int   bc = fc1[1][tid];
        bool take = (b1 < a1) || (b1 == a1 && bc < ac);
        float V1 = take ? b1 : a1;
        int   C1 = take ? bc : ac;
        float V2 = take ? fminf(a1, b2) : fminf(a2, b1);
        winner[row0 + tid] = C1;
        if (V2 - V1 < AMB_EPS) {
            int p = atomicAdd(amb_count, 1);
            if (p < AMB_CAP) amb_list[p] = (int)(row0 + tid);
        }
    }
}

// ---------------- recheck v2: batched exact R2-chain argmin ----------------
// 8 rows/batch staged transposed in LDS; each thread keeps codes {tid,tid+256,
// tid+512,tid+768} with the identical sequential 16x32-chunk association.
#define RB 8
#define ZSR 9   // padded row stride in zs (breaks bank conflicts on staging writes)
__global__ __launch_bounds__(256) void vq_recheck(const float* __restrict__ z,
                                                  const float* __restrict__ cb,
                                                  const float* __restrict__ ws,
                                                  int* __restrict__ winner,
                                                  const int* __restrict__ amb_count,
                                                  const int* __restrict__ amb_list) {
    __shared__ float zs[EDIM * ZSR];     // [k][r] transposed, 18KB
    __shared__ float wred_d[4];
    __shared__ int   wred_i[4];
    const int tid = threadIdx.x;
    const int lane = tid & 63, wv = tid >> 6;
    const float* __restrict__ enorm = ws + WS_ENORM;

    int n = *amb_count;
    bool overflow = (n > AMB_CAP);
    if (overflow) n = N_ROWS;            // safety net: recheck every row
    int nIter = (n + RB - 1) / RB;

    const float* ec[4];
    float en4[4];
    #pragma unroll
    for (int c = 0; c < 4; ++c) {
        ec[c]  = cb + (size_t)(tid + 256 * c) * EDIM;
        en4[c] = enorm[tid + 256 * c];
    }

    for (int ii = blockIdx.x; ii < nIter; ii += gridDim.x) {
        int rows[RB];
        #pragma unroll
        for (int j = 0; j < RB; ++j) {
            int idx = ii * RB + j;
            if (idx >= n) idx = n - 1;
            rows[j] = overflow ? idx : amb_list[idx];
        }
        __syncthreads();
        #pragma unroll
        for (int j = 0; j < RB; ++j) {
            float2 v = *(const float2*)&z[(long)rows[j] * EDIM + tid * 2];
            zs[(tid * 2 + 0) * ZSR + j] = v.x;
            zs[(tid * 2 + 1) * ZSR + j] = v.y;
        }
        __syncthreads();

        float acc[RB][4];
        #pragma unroll
        for (int r = 0; r < RB; ++r)
            #pragma unroll
            for (int c = 0; c < 4; ++c) acc[r][c] = 0.0f;

        for (int k0 = 0; k0 < EDIM; k0 += 32) {
            float ain[RB][4];
            #pragma unroll
            for (int r = 0; r < RB; ++r)
                #pragma unroll
                for (int c = 0; c < 4; ++c) ain[r][c] = 0.0f;
            #pragma unroll
            for (int ks = 0; ks < 32; ks += 8) {
                float er[4][8];
                #pragma unroll
                for (int c = 0; c < 4; ++c) {
                    float4 a = *(const float4*)&ec[c][k0 + ks];
                    float4 b = *(const float4*)&ec[c][k0 + ks + 4];
                    er[c][0]=a.x; er[c][1]=a.y; er[c][2]=a.z; er[c][3]=a.w;
                    er[c][4]=b.x; er[c][5]=b.y; er[c][6]=b.z; er[c][7]=b.w;
                }
                #pragma unroll
                for (int kk = 0; kk < 8; ++kk) {
                    const float* zp = &zs[(k0 + ks + kk) * ZSR];
                    float4 z0 = *(const float4*)zp;       // rows 0..3 (broadcast)
                    float4 z1 = *(const float4*)(zp + 4); // rows 4..7
                    float zr[RB] = {z0.x, z0.y, z0.z, z0.w, z1.x, z1.y, z1.z, z1.w};
                    #pragma unroll
                    for (int r = 0; r < RB; ++r)
                        #pragma unroll
                        for (int c = 0; c < 4; ++c)
                            ain[r][c] = fmaf(zr[r], er[c][kk], ain[r][c]);
                }
            }
            #pragma unroll
            for (int r = 0; r < RB; ++r)
                #pragma unroll
                for (int c = 0; c < 4; ++c) acc[r][c] += ain[r][c];
        }

        // per-row: d = fl(fl(zn+en) - 2*acc), first-index argmin
        #pragma unroll
        for (int r = 0; r < RB; ++r) {
            float zn = ws[WS_ZNORM + rows[r]];
            float bd = INFINITY;
            int   bc = 0;
            #pragma unroll
            for (int c = 0; c < 4; ++c) {        // codes ascending per thread
                float t = zn + en4[c];
                float d = t - 2.0f * acc[r][c];
                if (d < bd) { bd = d; bc = tid + 256 * c; }
            }
            // wave reduce with index tiebreak
            #pragma unroll
            for (int off = 1; off < 64; off <<= 1) {
                float od = __shfl_xor(bd, off);
                int   oi = __shfl_xor(bc, off);
                if (od < bd || (od == bd && oi < bc)) { bd = od; bc = oi; }
            }
            if (lane == 0) { wred_d[wv] = bd; wred_i[wv] = bc; }
            __syncthreads();
            if (tid == 0) {
                float fd = wred_d[0]; int fi = wred_i[0];
                #pragma unroll
                for (int t2 = 1; t2 < 4; ++t2) {
                    if (wred_d[t2] < fd || (wred_d[t2] == fd && wred_i[t2] < fi)) {
                        fd = wred_d[t2]; fi = wred_i[t2];
                    }
                }
                winner[rows[r]] = fi;
            }
            __syncthreads();
        }
    }
}

// ---------------- emit: idx, counts, z_q_st, loss ----------------
__global__ __launch_bounds__(256) void vq_emit(const float* __restrict__ z,
                                               const float* __restrict__ cb,
                                               const int* __restrict__ winner,
                                               float* __restrict__ ws,
                                               float* __restrict__ out_zq,
                                               float* __restrict__ out_idx) {
    __shared__ float lred[4];
    const int tid = threadIdx.x;
    const long row0 = (long)blockIdx.x * 128;
    if (tid < 128) {
        int wi = winner[row0 + tid];
        out_idx[row0 + tid] = (float)wi;
        atomicAdd(&ws[WS_COUNTS + wi], 1.0f);
    }
    float lsum = 0.0f;
    for (int r = 0; r < 128; ++r) {
        int wv = winner[row0 + r];
        float2 e  = *(const float2*)&cb[(size_t)wv * EDIM + tid * 2];
        float2 zz = *(const float2*)&z[(row0 + r) * EDIM + tid * 2];
        float d0 = e.x - zz.x, d1 = e.y - zz.y;
        float2 o; o.x = zz.x + d0; o.y = zz.y + d1;
        *(float2*)&out_zq[(row0 + r) * EDIM + tid * 2] = o;
        lsum = fmaf(d0, d0, fmaf(d1, d1, lsum));
    }
    #pragma unroll
    for (int off = 32; off > 0; off >>= 1) lsum += __shfl_down(lsum, off);
    int wave = tid >> 6, lane = tid & 63;
    if (lane == 0) lred[wave] = lsum;
    __syncthreads();
    if (tid == 0) atomicAdd(&ws[WS_LOSS], lred[0] + lred[1] + lred[2] + lred[3]);
}

// ---------------- finalize loss + perplexity ----------------
__global__ __launch_bounds__(1024) void vq_final(const float* __restrict__ ws,
                                                 float* __restrict__ out,
                                                 long off_perp) {
    int tid = threadIdx.x;
    float c = ws[WS_COUNTS + tid] * (1.0f / (float)N_ROWS);
    float t = c * logf(c + 1e-10f);
    #pragma unroll
    for (int off = 32; off > 0; off >>= 1) t += __shfl_down(t, off);
    __shared__ float ls[16];
    int wave = tid >> 6, lane = tid & 63;
    if (lane == 0) ls[wave] = t;
    __syncthreads();
    if (tid == 0) {
        float h = 0.0f;
        #pragma unroll
        for (int i = 0; i < 16; ++i) h += ls[i];
        out[off_perp] = expf(-h);
        out[0] = ws[WS_LOSS] * 1.25f / (float)((long)N_ROWS * EDIM);
    }
}

// ================= fallback: round-2 verified fp32 main kernel =================
#define ROWS_PER_BLOCK 128
#define CODE_CHUNK     64
#define KCHUNK         32
#define ZSTRIDE        132
#define ESTRIDE        68

__global__ __launch_bounds__(256) void vq_main_fb(const float* __restrict__ z,
                                                  const float* __restrict__ cb,
                                                  float* __restrict__ ws,
                                                  float* __restrict__ out_zq,
                                                  float* __restrict__ out_idx) {
    __shared__ float zt[KCHUNK * ZSTRIDE];
    __shared__ float et[KCHUNK * ESTRIDE];
    __shared__ float red_d[ROWS_PER_BLOCK * 8];
    __shared__ int   red_i[ROWS_PER_BLOCK * 8];
    __shared__ int   winner[ROWS_PER_BLOCK];
    __shared__ float lred[4];

    const int tid = threadIdx.x;
    const int tx = tid & 7;
    const int ty = tid >> 3;
    const long row0 = (long)blockIdx.x * ROWS_PER_BLOCK;
    const float* __restrict__ enorm = ws + WS_ENORM;
    const float* __restrict__ znorm = ws + WS_ZNORM;

    float zn[4];
    #pragma unroll
    for (int i = 0; i < 4; ++i) zn[i] = znorm[row0 + ty * 4 + i];

    float best[4];
    int   bidx[4];
    #pragma unroll
    for (int i = 0; i < 4; ++i) { best[i] = INFINITY; bidx[i] = 0; }

    const int kq    = (tid & 7) * 4;
    const int rbase = tid >> 3;

    for (int c = 0; c < NCODES; c += CODE_CHUNK) {
        float acc[4][8];
        #pragma unroll
        for (int i = 0; i < 4; ++i)
            #pragma unroll
            for (int j = 0; j < 8; ++j) acc[i][j] = 0.0f;

        for (int k0 = 0; k0 < EDIM; k0 += KCHUNK) {
            __syncthreads();
            #pragma unroll
            for (int it = 0; it < 4; ++it) {
                int r = rbase + it * 32;
                float4 v = *(const float4*)&z[(row0 + r) * EDIM + k0 + kq];
                zt[(kq + 0) * ZSTRIDE + r] = v.x;
                zt[(kq + 1) * ZSTRIDE + r] = v.y;
                zt[(kq + 2) * ZSTRIDE + r] = v.z;
                zt[(kq + 3) * ZSTRIDE + r] = v.w;
            }
            #pragma unroll
            for (int it = 0; it < 2; ++it) {
                int e = rbase + it * 32;
                float4 v = *(const float4*)&cb[(size_t)(c + e) * EDIM + k0 + kq];
                et[(kq + 0) * ESTRIDE + e] = v.x;
                et[(kq + 1) * ESTRIDE + e] = v.y;
                et[(kq + 2) * ESTRIDE + e] = v.z;
                et[(kq + 3) * ESTRIDE + e] = v.w;
            }
            __syncthreads();
            float ain[4][8];
            #pragma unroll
            for (int i = 0; i < 4; ++i)
                #pragma unroll
                for (int j = 0; j < 8; ++j) ain[i][j] = 0.0f;
            #pragma unroll
            for (int kk = 0; kk < KCHUNK; ++kk) {
                float4 zv = *(const float4*)&zt[kk * ZSTRIDE + ty * 4];
                float4 e0 = *(const float4*)&et[kk * ESTRIDE + tx * 8];
                float4 e1 = *(const float4*)&et[kk * ESTRIDE + tx * 8 + 4];
                float za[4] = {zv.x, zv.y, zv.z, zv.w};
                float ea[8] = {e0.x, e0.y, e0.z, e0.w, e1.x, e1.y, e1.z, e1.w};
                #pragma unroll
                for (int i = 0; i < 4; ++i)
                    #pragma unroll
                    for (int j = 0; j < 8; ++j)
                        ain[i][j] = fmaf(za[i], ea[j], ain[i][j]);
            }
            #pragma unroll
            for (int i = 0; i < 4; ++i)
                #pragma unroll
                for (int j = 0; j < 8; ++j) acc[i][j] += ain[i][j];
        }
        #pragma unroll
        for (int j = 0; j < 8; ++j) {
            int code = c + tx * 8 + j;
            float en = enorm[code];
            #pragma unroll
            for (int i = 0; i < 4; ++i) {
                float t = zn[i] + en;
                float d = t - 2.0f * acc[i][j];
                if (d < best[i]) { best[i] = d; bidx[i] = code; }
            }
        }
    }

    __syncthreads();
    #pragma unroll
    for (int i = 0; i < 4; ++i) {
        red_d[(ty * 4 + i) * 8 + tx] = best[i];
        red_i[(ty * 4 + i) * 8 + tx] = bidx[i];
    }
    __syncthreads();
    if (tid < ROWS_PER_BLOCK) {
        float bd = red_d[tid * 8];
        int   bi = red_i[tid * 8];
        #pragma unroll
        for (int t = 1; t < 8; ++t) {
            float dv = red_d[tid * 8 + t];
            int   iv = red_i[tid * 8 + t];
            if (dv < bd || (dv == bd && iv < bi)) { bd = dv; bi = iv; }
        }
        winner[tid] = bi;
        out_idx[row0 + tid] = (float)bi;
        atomicAdd(&ws[WS_COUNTS + bi], 1.0f);
    }
    __syncthreads();

    float lsum = 0.0f;
    for (int r = 0; r < ROWS_PER_BLOCK; ++r) {
        int w = winner[r];
        float2 e  = *(const float2*)&cb[(size_t)w * EDIM + tid * 2];
        float2 zz = *(const float2*)&z[(row0 + r) * EDIM + tid * 2];
        float d0 = e.x - zz.x, d1 = e.y - zz.y;
        float2 o; o.x = zz.x + d0; o.y = zz.y + d1;
        *(float2*)&out_zq[(row0 + r) * EDIM + tid * 2] = o;
        lsum = fmaf(d0, d0, fmaf(d1, d1, lsum));
    }
    #pragma unroll
    for (int off = 32; off > 0; off >>= 1) lsum += __shfl_down(lsum, off);
    int wave = tid >> 6, lane = tid & 63;
    if (lane == 0) lred[wave] = lsum;
    __syncthreads();
    if (tid == 0) atomicAdd(&ws[WS_LOSS], lred[0] + lred[1] + lred[2] + lred[3]);
}

extern "C" void kernel_launch(void* const* d_in, const int* in_sizes, int n_in,
                              void* d_out, int out_size, void* d_ws, size_t ws_size,
                              hipStream_t stream) {
    const float* z  = (const float*)d_in[0];
    const float* cb = (const float*)d_in[1];
    float* out = (float*)d_out;
    float* ws  = (float*)d_ws;

    float* out_zq  = out + 1;
    float* out_idx = out + 1 + (long)N_ROWS * EDIM;
    long   off_perp = 1 + (long)N_ROWS * EDIM + N_ROWS;

    hipLaunchKernelGGL(vq_prep, dim3(NCODES), dim3(256), 0, stream, cb, ws);
    hipLaunchKernelGGL(vq_znorm, dim3(N_ROWS / 8), dim3(256), 0, stream, z, ws);

    if (ws_size >= (size_t)WS_FAST_BYTES) {
        // z2 scratch lives in the z_q output region (16B-aligned at out+4;
        // spills 12 B into the idx region, which emit rewrites afterwards)
        unsigned short* z2 = (unsigned short*)(out + 4);
        unsigned short* e2 = (unsigned short*)((char*)d_ws + WS_E2_OFF);
        int* winner    = ((int*)ws) + WS_WINNER;
        int* amb_count = ((int*)ws) + WS_AMBCNT;
        int* amb_list  = ((int*)ws) + WS_AMBLST;

        hipLaunchKernelGGL(vq_convz, dim3(N_ROWS / 128), dim3(256), 0, stream, z, z2);
        hipLaunchKernelGGL(vq_convcb, dim3(8), dim3(256), 0, stream, cb, e2);
        hipLaunchKernelGGL(vq_mfma, dim3(N_ROWS / 128), dim3(256), 0, stream,
                           z2, e2, ws, winner, amb_count, amb_list);
        hipLaunchKernelGGL(vq_recheck, dim3(1024), dim3(256), 0, stream,
                           z, cb, ws, winner, amb_count, amb_list);
        hipLaunchKernelGGL(vq_emit, dim3(N_ROWS / 128), dim3(256), 0, stream,
                           z, cb, winner, ws, out_zq, out_idx);
    } else {
        hipLaunchKernelGGL(vq_main_fb, dim3(N_ROWS / 128), dim3(256), 0, stream,
                           z, cb, ws, out_zq, out_idx);
    }
    hipLaunchKernelGGL(vq_final, dim3(1), dim3(1024), 0, stream, ws, out, off_perp);
}

// Round 3
// 680.002 us; speedup vs baseline: 1.1020x; 1.0496x over previous
//
#include <hip/hip_runtime.h>
#include <hip/hip_bf16.h>

// Problem constants
#define N_ROWS 65536   // 16*4096
#define EDIM   512
#define NCODES 1024

// ws layout (floats): [0]=loss, [1..1025)=counts, [1025..2049)=enorm, [2049..)=znorm
#define WS_LOSS   0
#define WS_COUNTS 1
#define WS_ENORM  1025
#define WS_ZNORM  2049
#define WS_AMBCNT (2049 + 65536)          // int, 67585
#define WS_WINNER (WS_AMBCNT + 1)         // 65536 ints
#define WS_AMBLST (WS_WINNER + 65536)     // CAP ints
#define AMB_CAP   32768
#define WS_E2_OFF (1u << 20)              // e2 (bf16 hi/lo) at ws + 1 MiB, 2 MiB
#define WS_FAST_BYTES (3u * 1024u * 1024u + 4096u)

// δ bound: ref quantization 2×ULP(512)/2 = 6.1e-5, ref-vs-my dot ≈ 6.3e-6 → pair 1.35e-4
#define AMB_EPS 1.6e-4f

typedef short short8 __attribute__((ext_vector_type(8)));
typedef float f32x4  __attribute__((ext_vector_type(4)));

#define AS1C(p) ((const __attribute__((address_space(1))) void*)(p))
#define AS3(p)  ((__attribute__((address_space(3))) void*)(p))

static __device__ __forceinline__ unsigned short f2bf(float f) {
    unsigned u = __float_as_uint(f);
    u += 0x7FFFu + ((u >> 16) & 1u);   // RNE (finite inputs only)
    return (unsigned short)(u >> 16);
}
static __device__ __forceinline__ float bf2f(unsigned short h) {
    return __uint_as_float(((unsigned)h) << 16);
}

// ---------------- kernel: codebook norms + zero accumulators ----------------
__global__ __launch_bounds__(256) void vq_prep(const float* __restrict__ cb,
                                               float* __restrict__ ws) {
    int j = blockIdx.x;
    int tid = threadIdx.x;
    float2 v = *(const float2*)&cb[(size_t)j * EDIM + tid * 2];
    float s = v.x * v.x + v.y * v.y;
    #pragma unroll
    for (int off = 32; off > 0; off >>= 1) s += __shfl_down(s, off);
    __shared__ float ls[4];
    int wave = tid >> 6, lane = tid & 63;
    if (lane == 0) ls[wave] = s;
    __syncthreads();
    if (tid == 0) {
        ws[WS_ENORM + j] = ls[0] + ls[1] + ls[2] + ls[3];
        ws[WS_COUNTS + j] = 0.0f;
        if (j == 0) {
            ws[WS_LOSS] = 0.0f;
            ((int*)ws)[WS_AMBCNT] = 0;
        }
    }
}

// ---------------- kernel: per-row ||z||^2, numpy-pairwise bit-exact ----------------
__global__ __launch_bounds__(256) void vq_znorm(const float* __restrict__ z,
                                                float* __restrict__ ws) {
    int tid  = threadIdx.x;
    int lrow = tid >> 5;
    int c    = tid & 31;
    long row = (long)blockIdx.x * 8 + lrow;
    const float* p = z + row * EDIM + (c >> 3) * 128 + (c & 7);
    float r = p[0] * p[0];
    #pragma unroll
    for (int i = 1; i < 16; ++i) {
        float v = p[i * 8];
        r += v * v;
    }
    r += __shfl_xor(r, 1);
    r += __shfl_xor(r, 2);
    r += __shfl_xor(r, 4);
    r += __shfl_xor(r, 8);
    r += __shfl_xor(r, 16);
    if (c == 0) ws[WS_ZNORM + row] = r;
}

// ---------------- kernel: z -> bf16 hi/lo panels ----------------
// layout: [panel p][kc 0..15][plane hi/lo][row 0..127][k 0..31] ushort
__global__ __launch_bounds__(256) void vq_convz(const float* __restrict__ z,
                                                unsigned short* __restrict__ z2) {
    const int tid = threadIdx.x;
    const int p = blockIdx.x;
    const long row0 = (long)p * 128;
    const int row = tid >> 1, half = tid & 1;
    for (int kc = 0; kc < 16; ++kc) {
        const float* src = z + (row0 + row) * EDIM + kc * 32 + half * 16;
        float f[16];
        #pragma unroll
        for (int q = 0; q < 4; ++q) {
            float4 v = ((const float4*)src)[q];
            f[q*4+0] = v.x; f[q*4+1] = v.y; f[q*4+2] = v.z; f[q*4+3] = v.w;
        }
        unsigned hi[8], lo[8];
        #pragma unroll
        for (int q = 0; q < 8; ++q) {
            unsigned short h0 = f2bf(f[2*q]);
            unsigned short h1 = f2bf(f[2*q+1]);
            unsigned short l0 = f2bf(f[2*q]   - bf2f(h0));
            unsigned short l1 = f2bf(f[2*q+1] - bf2f(h1));
            hi[q] = (unsigned)h0 | ((unsigned)h1 << 16);
            lo[q] = (unsigned)l0 | ((unsigned)l1 << 16);
        }
        size_t base = ((size_t)(p * 16 + kc) * 2) * 4096;
        unsigned* dhi = (unsigned*)(z2 + base        + row * 32 + half * 16);
        unsigned* dlo = (unsigned*)(z2 + base + 4096 + row * 32 + half * 16);
        ((uint4*)dhi)[0] = make_uint4(hi[0], hi[1], hi[2], hi[3]);
        ((uint4*)dhi)[1] = make_uint4(hi[4], hi[5], hi[6], hi[7]);
        ((uint4*)dlo)[0] = make_uint4(lo[0], lo[1], lo[2], lo[3]);
        ((uint4*)dlo)[1] = make_uint4(lo[4], lo[5], lo[6], lo[7]);
    }
}

// ---------------- kernel: cb -> bf16 hi/lo panels ----------------
// layout: [cc 0..7][kc 0..15][plane][code 0..127][k 0..31]
__global__ __launch_bounds__(256) void vq_convcb(const float* __restrict__ cb,
                                                 unsigned short* __restrict__ e2) {
    const int tid = threadIdx.x;
    const int cc = blockIdx.x;
    const int row = tid >> 1, half = tid & 1;
    for (int kc = 0; kc < 16; ++kc) {
        const float* src = cb + (size_t)(cc * 128 + row) * EDIM + kc * 32 + half * 16;
        float f[16];
        #pragma unroll
        for (int q = 0; q < 4; ++q) {
            float4 v = ((const float4*)src)[q];
            f[q*4+0] = v.x; f[q*4+1] = v.y; f[q*4+2] = v.z; f[q*4+3] = v.w;
        }
        unsigned hi[8], lo[8];
        #pragma unroll
        for (int q = 0; q < 8; ++q) {
            unsigned short h0 = f2bf(f[2*q]);
            unsigned short h1 = f2bf(f[2*q+1]);
            unsigned short l0 = f2bf(f[2*q]   - bf2f(h0));
            unsigned short l1 = f2bf(f[2*q+1] - bf2f(h1));
            hi[q] = (unsigned)h0 | ((unsigned)h1 << 16);
            lo[q] = (unsigned)l0 | ((unsigned)l1 << 16);
        }
        size_t base = ((size_t)(cc * 16 + kc) * 2) * 4096;
        unsigned* dhi = (unsigned*)(e2 + base        + row * 32 + half * 16);
        unsigned* dlo = (unsigned*)(e2 + base + 4096 + row * 32 + half * 16);
        ((uint4*)dhi)[0] = make_uint4(hi[0], hi[1], hi[2], hi[3]);
        ((uint4*)dhi)[1] = make_uint4(hi[4], hi[5], hi[6], hi[7]);
        ((uint4*)dlo)[0] = make_uint4(lo[0], lo[1], lo[2], lo[3]);
        ((uint4*)dlo)[1] = make_uint4(lo[4], lo[5], lo[6], lo[7]);
    }
}

// ---------------- main MFMA kernel: d-hat + per-row top2 + ambiguity ----------------
// Round-3 structure: 256 rows x 256 codes per block, 8 waves (4 row-groups x
// 2 code-groups), wave tile 64x128 (rt=4, ct=8). One block/CU, 2 waves/SIMD.
// Rationale (round-0/1/2 counters): all prior shapes were staging-BW bound at
// ~48 FLOP/staged-byte (util ~40%). This tile doubles FLOP/staged-byte to 96:
// per step stage 64 KB vs per-SIMD matrix work 2x96x19.4 = 3725 cyc >= stage
// service time -> compute-bound. z2 logical reads halve (4 cc passes), e2
// logical halves (256 blocks).
// 2-phase pipeline: stage(s+1) into other buffer -> frag ds_reads + 96 MFMAs
// on current -> s_waitcnt vmcnt(0) -> raw s_barrier. LDS layout: 128B
// interleaved rows [row][hi|lo], slot ^= row&7 (round-2-verified, conflicts=0);
// linear LDS dest + pre-swizzled global source + swizzled frag reads.
// Per-(row,code) accumulation chain (hihi,hilo,lohi over kc 0..15 from zero)
// is bit-identical to the verified kernel, so AMB_EPS analysis holds.
__device__ __forceinline__ void stage_chunk(const char* src, char* dst, int goff0,
                                            int wb) {
    // 16 KB chunk: linear LDS dest (j*8192 + tid*16), swizzled global src.
    __builtin_amdgcn_global_load_lds(AS1C(src + goff0),        AS3(dst + wb),        16, 0, 0);
    __builtin_amdgcn_global_load_lds(AS1C(src + goff0 + 4096), AS3(dst + 8192 + wb), 16, 0, 0);
}

__device__ __forceinline__ void stage_step(const char* zb, const char* eb, char* buf,
                                           int goff0, int wb) {
    stage_chunk(zb,              buf,         goff0, wb);   // z rows 0..127
    stage_chunk(zb + 16 * 16384, buf + 16384, goff0, wb);   // z rows 128..255
    stage_chunk(eb,              buf + 32768, goff0, wb);   // e codes 0..127
    stage_chunk(eb + 16 * 16384, buf + 49152, goff0, wb);   // e codes 128..255
}

__global__ __launch_bounds__(512, 2) void vq_mfma(const unsigned short* __restrict__ z2,
                                                  const unsigned short* __restrict__ e2,
                                                  const float* __restrict__ ws,
                                                  int* __restrict__ winner,
                                                  int* __restrict__ amb_count,
                                                  int* __restrict__ amb_list) {
    __shared__ __attribute__((aligned(16))) char sb[2][65536];  // 128 KB double-buffer
    __shared__ float enorm_lds[NCODES];                         // 4 KB
    __shared__ float fv1[2][256];
    __shared__ float fv2[2][256];
    __shared__ int   fc1[2][256];

    const int tid  = threadIdx.x;
    const int lane = tid & 63, w = tid >> 6;
    const int wr   = (w & 3) * 64;     // wave row offset (0..192)
    const int wcg  = w >> 2;           // 0..1 code-group
    const int wc   = wcg * 128;        // wave code offset within 256-wide pass
    const int ml = lane & 15, kg = lane >> 4;
    const long row0 = (long)blockIdx.x * 256;

    // staging: per-lane swizzled GLOBAL source offset within a 16KB chunk.
    // LDS linear byte P = j*8192 + tid*16 -> row = j*64 + (tid>>3); row&7 is
    // j-invariant, so sl (and goff) differ only by +4096 between j=0,1.
    const int t3 = tid >> 3;
    const int sl = (tid & 7) ^ (t3 & 7);
    const int goff0 = t3 * 64 + (sl & 3) * 16 + (sl >> 2) * 8192;
    const int wb = w << 10;            // wave-uniform LDS base; HW adds lane*16

    // frag reads: logical (row, slot=plane*4+kg) at row*128 + (slot^(row&7))*16
    const int xr = ml & 7;             // row&7 == ml&7 (wr, rt*16 are multiples of 8)
    const int o0 = (kg ^ xr) * 16;           // hi plane slot
    const int o1 = ((4 + kg) ^ xr) * 16;     // lo plane slot
    const int za = (wr + ml) * 128;
    const int ea = 32768 + (wc + ml) * 128;

    // enorm -> LDS (keeps epilogue off the vmcnt path)
    enorm_lds[tid]       = ws[WS_ENORM + tid];
    enorm_lds[tid + 512] = ws[WS_ENORM + tid + 512];

    float v1[16], v2[16];
    int   c1[16];
    #pragma unroll
    for (int i = 0; i < 16; ++i) { v1[i] = INFINITY; v2[i] = INFINITY; c1[i] = 0; }

    const char* z2b = (const char*)z2 + (size_t)blockIdx.x * 2 * 16 * 16384;
    const char* e2b = (const char*)e2;

    f32x4 acc[4][8];
    #pragma unroll
    for (int rt = 0; rt < 4; ++rt)
        #pragma unroll
        for (int ct = 0; ct < 8; ++ct)
            acc[rt][ct] = (f32x4){0.f, 0.f, 0.f, 0.f};

    // prologue: stage step 0 (cc=0, kc=0) into buffer 0
    stage_step(z2b, e2b, sb[0], goff0, wb);
    __syncthreads();   // full drain once; buf0 ready

    int cur = 0;
    #pragma unroll 2
    for (int s = 0; s < 64; ++s) {
        // 1) issue NEXT step's stage into the other buffer
        if (s + 1 < 64) {
            const int s2 = s + 1, cc2 = s2 >> 4, kc2 = s2 & 15;
            stage_step(z2b + (size_t)kc2 * 16384,
                       e2b + (size_t)(cc2 * 32 + kc2) * 16384,
                       sb[cur ^ 1], goff0, wb);
        }
        // 2) frag reads + 96 MFMAs on current buffer (covers stage latency)
        const char* bz = sb[cur];
        short8 a[4][2];
        #pragma unroll
        for (int rt = 0; rt < 4; ++rt) {
            a[rt][0] = *(const short8*)(bz + za + rt * 2048 + o0);
            a[rt][1] = *(const short8*)(bz + za + rt * 2048 + o1);
        }
        #pragma unroll
        for (int ct = 0; ct < 8; ++ct) {
            short8 b0 = *(const short8*)(bz + ea + ct * 2048 + o0);
            short8 b1 = *(const short8*)(bz + ea + ct * 2048 + o1);
            #pragma unroll
            for (int rt = 0; rt < 4; ++rt) {
                acc[rt][ct] = __builtin_amdgcn_mfma_f32_16x16x32_bf16(a[rt][0], b0, acc[rt][ct], 0, 0, 0);
                acc[rt][ct] = __builtin_amdgcn_mfma_f32_16x16x32_bf16(a[rt][0], b1, acc[rt][ct], 0, 0, 0);
                acc[rt][ct] = __builtin_amdgcn_mfma_f32_16x16x32_bf16(a[rt][1], b0, acc[rt][ct], 0, 0, 0);
            }
        }
        // 3) my stage loads landed; raw barrier (no compiler lgkm/vm drain)
        asm volatile("s_waitcnt vmcnt(0)" ::: "memory");
        __builtin_amdgcn_s_barrier();
        asm volatile("" ::: "memory");
        cur ^= 1;

        // 4) per-cc epilogue (registers + static LDS only; overlaps next stage)
        if ((s & 15) == 15) {
            const int cc = s >> 4;
            #pragma unroll
            for (int ct = 0; ct < 8; ++ct) {
                const int code = cc * 256 + wc + ct * 16 + ml;
                const float en = enorm_lds[code];
                #pragma unroll
                for (int rt = 0; rt < 4; ++rt)
                    #pragma unroll
                    for (int reg = 0; reg < 4; ++reg) {
                        float d = fmaf(-2.0f, acc[rt][ct][reg], en);
                        int i = rt * 4 + reg;
                        bool lt1 = d < v1[i];
                        bool lt2 = d < v2[i];
                        v2[i] = lt1 ? v1[i] : (lt2 ? d : v2[i]);
                        v1[i] = lt1 ? d : v1[i];
                        c1[i] = lt1 ? code : c1[i];
                    }
            }
            #pragma unroll
            for (int rt = 0; rt < 4; ++rt)
                #pragma unroll
                for (int ct = 0; ct < 8; ++ct)
                    acc[rt][ct] = (f32x4){0.f, 0.f, 0.f, 0.f};
        }
    }

    // cross-lane merge among the 16 lanes (same kg) sharing each row
    #pragma unroll
    for (int i = 0; i < 16; ++i) {
        #pragma unroll
        for (int off = 1; off < 16; off <<= 1) {
            float ov1 = __shfl_xor(v1[i], off);
            int   oc1 = __shfl_xor(c1[i], off);
            float ov2 = __shfl_xor(v2[i], off);
            bool take = (ov1 < v1[i]) || (ov1 == v1[i] && oc1 < c1[i]);
            float nv2 = take ? fminf(v1[i], ov2) : fminf(v2[i], ov1);
            v1[i] = take ? ov1 : v1[i];
            c1[i] = take ? oc1 : c1[i];
            v2[i] = nv2;
        }
    }
    __syncthreads();
    if (ml == 0) {
        #pragma unroll
        for (int i = 0; i < 16; ++i) {
            int row = wr + (i >> 2) * 16 + kg * 4 + (i & 3);
            fv1[wcg][row] = v1[i];
            fv2[wcg][row] = v2[i];
            fc1[wcg][row] = c1[i];
        }
    }
    __syncthreads();
    if (tid < 256) {
        float a1 = fv1[0][tid], a2 = fv2[0][tid];
        int   ac = fc1[0][tid];
        float b1 = fv1[1][tid], b2 = fv2[1][tid];
        int   bc = fc1[1][tid];
        bool take = (b1 < a1) || (b1 == a1 && bc < ac);
        float V1 = take ? b1 : a1;
        int   C1 = take ? bc : ac;
        float V2 = take ? fminf(a1, b2) : fminf(a2, b1);
        winner[row0 + tid] = C1;
        if (V2 - V1 < AMB_EPS) {
            int p = atomicAdd(amb_count, 1);
            if (p < AMB_CAP) amb_list[p] = (int)(row0 + tid);
        }
    }
}

// ---------------- recheck v2: batched exact R2-chain argmin ----------------
// 8 rows/batch staged transposed in LDS; each thread keeps codes {tid,tid+256,
// tid+512,tid+768} with the identical sequential 16x32-chunk association.
#define RB 8
#define ZSR 9   // padded row stride in zs (breaks bank conflicts on staging writes)
__global__ __launch_bounds__(256) void vq_recheck(const float* __restrict__ z,
                                                  const float* __restrict__ cb,
                                                  const float* __restrict__ ws,
                                                  int* __restrict__ winner,
                                                  const int* __restrict__ amb_count,
                                                  const int* __restrict__ amb_list) {
    __shared__ float zs[EDIM * ZSR];     // [k][r] transposed, 18KB
    __shared__ float wred_d[4];
    __shared__ int   wred_i[4];
    const int tid = threadIdx.x;
    const int lane = tid & 63, wv = tid >> 6;
    const float* __restrict__ enorm = ws + WS_ENORM;

    int n = *amb_count;
    bool overflow = (n > AMB_CAP);
    if (overflow) n = N_ROWS;            // safety net: recheck every row
    int nIter = (n + RB - 1) / RB;

    const float* ec[4];
    float en4[4];
    #pragma unroll
    for (int c = 0; c < 4; ++c) {
        ec[c]  = cb + (size_t)(tid + 256 * c) * EDIM;
        en4[c] = enorm[tid + 256 * c];
    }

    for (int ii = blockIdx.x; ii < nIter; ii += gridDim.x) {
        int rows[RB];
        #pragma unroll
        for (int j = 0; j < RB; ++j) {
            int idx = ii * RB + j;
            if (idx >= n) idx = n - 1;
            rows[j] = overflow ? idx : amb_list[idx];
        }
        __syncthreads();
        #pragma unroll
        for (int j = 0; j < RB; ++j) {
            float2 v = *(const float2*)&z[(long)rows[j] * EDIM + tid * 2];
            zs[(tid * 2 + 0) * ZSR + j] = v.x;
            zs[(tid * 2 + 1) * ZSR + j] = v.y;
        }
        __syncthreads();

        float acc[RB][4];
        #pragma unroll
        for (int r = 0; r < RB; ++r)
            #pragma unroll
            for (int c = 0; c < 4; ++c) acc[r][c] = 0.0f;

        for (int k0 = 0; k0 < EDIM; k0 += 32) {
            float ain[RB][4];
            #pragma unroll
            for (int r = 0; r < RB; ++r)
                #pragma unroll
                for (int c = 0; c < 4; ++c) ain[r][c] = 0.0f;
            #pragma unroll
            for (int ks = 0; ks < 32; ks += 8) {
                float er[4][8];
                #pragma unroll
                for (int c = 0; c < 4; ++c) {
                    float4 a = *(const float4*)&ec[c][k0 + ks];
                    float4 b = *(const float4*)&ec[c][k0 + ks + 4];
                    er[c][0]=a.x; er[c][1]=a.y; er[c][2]=a.z; er[c][3]=a.w;
                    er[c][4]=b.x; er[c][5]=b.y; er[c][6]=b.z; er[c][7]=b.w;
                }
                #pragma unroll
                for (int kk = 0; kk < 8; ++kk) {
                    const float* zp = &zs[(k0 + ks + kk) * ZSR];
                    float4 z0 = *(const float4*)zp;       // rows 0..3 (broadcast)
                    float4 z1 = *(const float4*)(zp + 4); // rows 4..7
                    float zr[RB] = {z0.x, z0.y, z0.z, z0.w, z1.x, z1.y, z1.z, z1.w};
                    #pragma unroll
                    for (int r = 0; r < RB; ++r)
                        #pragma unroll
                        for (int c = 0; c < 4; ++c)
                            ain[r][c] = fmaf(zr[r], er[c][kk], ain[r][c]);
                }
            }
            #pragma unroll
            for (int r = 0; r < RB; ++r)
                #pragma unroll
                for (int c = 0; c < 4; ++c) acc[r][c] += ain[r][c];
        }

        // per-row: d = fl(fl(zn+en) - 2*acc), first-index argmin
        #pragma unroll
        for (int r = 0; r < RB; ++r) {
            float zn = ws[WS_ZNORM + rows[r]];
            float bd = INFINITY;
            int   bc = 0;
            #pragma unroll
            for (int c = 0; c < 4; ++c) {        // codes ascending per thread
                float t = zn + en4[c];
                float d = t - 2.0f * acc[r][c];
                if (d < bd) { bd = d; bc = tid + 256 * c; }
            }
            // wave reduce with index tiebreak
            #pragma unroll
            for (int off = 1; off < 64; off <<= 1) {
                float od = __shfl_xor(bd, off);
                int   oi = __shfl_xor(bc, off);
                if (od < bd || (od == bd && oi < bc)) { bd = od; bc = oi; }
            }
            if (lane == 0) { wred_d[wv] = bd; wred_i[wv] = bc; }
            __syncthreads();
            if (tid == 0) {
                float fd = wred_d[0]; int fi = wred_i[0];
                #pragma unroll
                for (int t2 = 1; t2 < 4; ++t2) {
                    if (wred_d[t2] < fd || (wred_d[t2] == fd && wred_i[t2] < fi)) {
                        fd = wred_d[t2]; fi = wred_i[t2];
                    }
                }
                winner[rows[r]] = fi;
            }
            __syncthreads();
        }
    }
}

// ---------------- emit: idx, counts, z_q_st, loss ----------------
__global__ __launch_bounds__(256) void vq_emit(const float* __restrict__ z,
                                               const float* __restrict__ cb,
                                               const int* __restrict__ winner,
                                               float* __restrict__ ws,
                                               float* __restrict__ out_zq,
                                               float* __restrict__ out_idx) {
    __shared__ float lred[4];
    const int tid = threadIdx.x;
    const long row0 = (long)blockIdx.x * 128;
    if (tid < 128) {
        int wi = winner[row0 + tid];
        out_idx[row0 + tid] = (float)wi;
        atomicAdd(&ws[WS_COUNTS + wi], 1.0f);
    }
    float lsum = 0.0f;
    for (int r = 0; r < 128; ++r) {
        int wv = winner[row0 + r];
        float2 e  = *(const float2*)&cb[(size_t)wv * EDIM + tid * 2];
        float2 zz = *(const float2*)&z[(row0 + r) * EDIM + tid * 2];
        float d0 = e.x - zz.x, d1 = e.y - zz.y;
        float2 o; o.x = zz.x + d0; o.y = zz.y + d1;
        *(float2*)&out_zq[(row0 + r) * EDIM + tid * 2] = o;
        lsum = fmaf(d0, d0, fmaf(d1, d1, lsum));
    }
    #pragma unroll
    for (int off = 32; off > 0; off >>= 1) lsum += __shfl_down(lsum, off);
    int wave = tid >> 6, lane = tid & 63;
    if (lane == 0) lred[wave] = lsum;
    __syncthreads();
    if (tid == 0) atomicAdd(&ws[WS_LOSS], lred[0] + lred[1] + lred[2] + lred[3]);
}

// ---------------- finalize loss + perplexity ----------------
__global__ __launch_bounds__(1024) void vq_final(const float* __restrict__ ws,
                                                 float* __restrict__ out,
                                                 long off_perp) {
    int tid = threadIdx.x;
    float c = ws[WS_COUNTS + tid] * (1.0f / (float)N_ROWS);
    float t = c * logf(c + 1e-10f);
    #pragma unroll
    for (int off = 32; off > 0; off >>= 1) t += __shfl_down(t, off);
    __shared__ float ls[16];
    int wave = tid >> 6, lane = tid & 63;
    if (lane == 0) ls[wave] = t;
    __syncthreads();
    if (tid == 0) {
        float h = 0.0f;
        #pragma unroll
        for (int i = 0; i < 16; ++i) h += ls[i];
        out[off_perp] = expf(-h);
        out[0] = ws[WS_LOSS] * 1.25f / (float)((long)N_ROWS * EDIM);
    }
}

// ================= fallback: round-2 verified fp32 main kernel =================
#define ROWS_PER_BLOCK 128
#define CODE_CHUNK     64
#define KCHUNK         32
#define ZSTRIDE        132
#define ESTRIDE        68

__global__ __launch_bounds__(256) void vq_main_fb(const float* __restrict__ z,
                                                  const float* __restrict__ cb,
                                                  float* __restrict__ ws,
                                                  float* __restrict__ out_zq,
                                                  float* __restrict__ out_idx) {
    __shared__ float zt[KCHUNK * ZSTRIDE];
    __shared__ float et[KCHUNK * ESTRIDE];
    __shared__ float red_d[ROWS_PER_BLOCK * 8];
    __shared__ int   red_i[ROWS_PER_BLOCK * 8];
    __shared__ int   winner[ROWS_PER_BLOCK];
    __shared__ float lred[4];

    const int tid = threadIdx.x;
    const int tx = tid & 7;
    const int ty = tid >> 3;
    const long row0 = (long)blockIdx.x * ROWS_PER_BLOCK;
    const float* __restrict__ enorm = ws + WS_ENORM;
    const float* __restrict__ znorm = ws + WS_ZNORM;

    float zn[4];
    #pragma unroll
    for (int i = 0; i < 4; ++i) zn[i] = znorm[row0 + ty * 4 + i];

    float best[4];
    int   bidx[4];
    #pragma unroll
    for (int i = 0; i < 4; ++i) { best[i] = INFINITY; bidx[i] = 0; }

    const int kq    = (tid & 7) * 4;
    const int rbase = tid >> 3;

    for (int c = 0; c < NCODES; c += CODE_CHUNK) {
        float acc[4][8];
        #pragma unroll
        for (int i = 0; i < 4; ++i)
            #pragma unroll
            for (int j = 0; j < 8; ++j) acc[i][j] = 0.0f;

        for (int k0 = 0; k0 < EDIM; k0 += KCHUNK) {
            __syncthreads();
            #pragma unroll
            for (int it = 0; it < 4; ++it) {
                int r = rbase + it * 32;
                float4 v = *(const float4*)&z[(row0 + r) * EDIM + k0 + kq];
                zt[(kq + 0) * ZSTRIDE + r] = v.x;
                zt[(kq + 1) * ZSTRIDE + r] = v.y;
                zt[(kq + 2) * ZSTRIDE + r] = v.z;
                zt[(kq + 3) * ZSTRIDE + r] = v.w;
            }
            #pragma unroll
            for (int it = 0; it < 2; ++it) {
                int e = rbase + it * 32;
                float4 v = *(const float4*)&cb[(size_t)(c + e) * EDIM + k0 + kq];
                et[(kq + 0) * ESTRIDE + e] = v.x;
                et[(kq + 1) * ESTRIDE + e] = v.y;
                et[(kq + 2) * ESTRIDE + e] = v.z;
                et[(kq + 3) * ESTRIDE + e] = v.w;
            }
            __syncthreads();
            float ain[4][8];
            #pragma unroll
            for (int i = 0; i < 4; ++i)
                #pragma unroll
                for (int j = 0; j < 8; ++j) ain[i][j] = 0.0f;
            #pragma unroll
            for (int kk = 0; kk < KCHUNK; ++kk) {
                float4 zv = *(const float4*)&zt[kk * ZSTRIDE + ty * 4];
                float4 e0 = *(const float4*)&et[kk * ESTRIDE + tx * 8];
                float4 e1 = *(const float4*)&et[kk * ESTRIDE + tx * 8 + 4];
                float za[4] = {zv.x, zv.y, zv.z, zv.w};
                float ea[8] = {e0.x, e0.y, e0.z, e0.w, e1.x, e1.y, e1.z, e1.w};
                #pragma unroll
                for (int i = 0; i < 4; ++i)
                    #pragma unroll
                    for (int j = 0; j < 8; ++j)
                        ain[i][j] = fmaf(za[i], ea[j], ain[i][j]);
            }
            #pragma unroll
            for (int i = 0; i < 4; ++i)
                #pragma unroll
                for (int j = 0; j < 8; ++j) acc[i][j] += ain[i][j];
        }
        #pragma unroll
        for (int j = 0; j < 8; ++j) {
            int code = c + tx * 8 + j;
            float en = enorm[code];
            #pragma unroll
            for (int i = 0; i < 4; ++i) {
                float t = zn[i] + en;
                float d = t - 2.0f * acc[i][j];
                if (d < best[i]) { best[i] = d; bidx[i] = code; }
            }
        }
    }

    __syncthreads();
    #pragma unroll
    for (int i = 0; i < 4; ++i) {
        red_d[(ty * 4 + i) * 8 + tx] = best[i];
        red_i[(ty * 4 + i) * 8 + tx] = bidx[i];
    }
    __syncthreads();
    if (tid < ROWS_PER_BLOCK) {
        float bd = red_d[tid * 8];
        int   bi = red_i[tid * 8];
        #pragma unroll
        for (int t = 1; t < 8; ++t) {
            float dv = red_d[tid * 8 + t];
            int   iv = red_i[tid * 8 + t];
            if (dv < bd || (dv == bd && iv < bi)) { bd = dv; bi = iv; }
        }
        winner[tid] = bi;
        out_idx[row0 + tid] = (float)bi;
        atomicAdd(&ws[WS_COUNTS + bi], 1.0f);
    }
    __syncthreads();

    float lsum = 0.0f;
    for (int r = 0; r < ROWS_PER_BLOCK; ++r) {
        int w = winner[r];
        float2 e  = *(const float2*)&cb[(size_t)w * EDIM + tid * 2];
        float2 zz = *(const float2*)&z[(row0 + r) * EDIM + tid * 2];
        float d0 = e.x - zz.x, d1 = e.y - zz.y;
        float2 o; o.x = zz.x + d0; o.y = zz.y + d1;
        *(float2*)&out_zq[(row0 + r) * EDIM + tid * 2] = o;
        lsum = fmaf(d0, d0, fmaf(d1, d1, lsum));
    }
    #pragma unroll
    for (int off = 32; off > 0; off >>= 1) lsum += __shfl_down(lsum, off);
    int wave = tid >> 6, lane = tid & 63;
    if (lane == 0) lred[wave] = lsum;
    __syncthreads();
    if (tid == 0) atomicAdd(&ws[WS_LOSS], lred[0] + lred[1] + lred[2] + lred[3]);
}

extern "C" void kernel_launch(void* const* d_in, const int* in_sizes, int n_in,
                              void* d_out, int out_size, void* d_ws, size_t ws_size,
                              hipStream_t stream) {
    const float* z  = (const float*)d_in[0];
    const float* cb = (const float*)d_in[1];
    float* out = (float*)d_out;
    float* ws  = (float*)d_ws;

    float* out_zq  = out + 1;
    float* out_idx = out + 1 + (long)N_ROWS * EDIM;
    long   off_perp = 1 + (long)N_ROWS * EDIM + N_ROWS;

    hipLaunchKernelGGL(vq_prep, dim3(NCODES), dim3(256), 0, stream, cb, ws);
    hipLaunchKernelGGL(vq_znorm, dim3(N_ROWS / 8), dim3(256), 0, stream, z, ws);

    if (ws_size >= (size_t)WS_FAST_BYTES) {
        // z2 scratch lives in the z_q output region (16B-aligned at out+4;
        // spills 12 B into the idx region, which emit rewrites afterwards)
        unsigned short* z2 = (unsigned short*)(out + 4);
        unsigned short* e2 = (unsigned short*)((char*)d_ws + WS_E2_OFF);
        int* winner    = ((int*)ws) + WS_WINNER;
        int* amb_count = ((int*)ws) + WS_AMBCNT;
        int* amb_list  = ((int*)ws) + WS_AMBLST;

        hipLaunchKernelGGL(vq_convz, dim3(N_ROWS / 128), dim3(256), 0, stream, z, z2);
        hipLaunchKernelGGL(vq_convcb, dim3(8), dim3(256), 0, stream, cb, e2);
        hipLaunchKernelGGL(vq_mfma, dim3(N_ROWS / 256), dim3(512), 0, stream,
                           z2, e2, ws, winner, amb_count, amb_list);
        hipLaunchKernelGGL(vq_recheck, dim3(1024), dim3(256), 0, stream,
                           z, cb, ws, winner, amb_count, amb_list);
        hipLaunchKernelGGL(vq_emit, dim3(N_ROWS / 128), dim3(256), 0, stream,
                           z, cb, winner, ws, out_zq, out_idx);
    } else {
        hipLaunchKernelGGL(vq_main_fb, dim3(N_ROWS / 128), dim3(256), 0, stream,
                           z, cb, ws, out_zq, out_idx);
    }
    hipLaunchKernelGGL(vq_final, dim3(1), dim3(1024), 0, stream, ws, out, off_perp);
}